// Round 12
// baseline (339.869 us; speedup 1.0000x reference)
//
#include <hip/hip_runtime.h>
#include <hip/hip_bf16.h>

typedef __bf16 bf16x8 __attribute__((ext_vector_type(8)));
typedef float f32x4 __attribute__((ext_vector_type(4)));
typedef unsigned short u16;

constexpr int BATCH = 2, SEQ = 2048, DM = 2048, NH = 16, HD = 128;
constexpr int N3 = 3 * DM;          // 6144
constexpr int MROWS = BATCH * SEQ;  // 4096

__device__ __forceinline__ u16 f2bf(float f) {
  unsigned u = __builtin_bit_cast(unsigned, f);
  unsigned r = 0x7FFFu + ((u >> 16) & 1u);
  return (u16)((u + r) >> 16);
}

// async global->LDS, 16B per lane; LDS dest = wave-uniform base + lane*16
__device__ __forceinline__ void glds16(const u16* g, u16* l) {
  __builtin_amdgcn_global_load_lds(
      (const __attribute__((address_space(1))) unsigned*)(const void*)g,
      (__attribute__((address_space(3))) unsigned*)(void*)l, 16, 0, 0);
}

// ---------------- convert f32 -> bf16 (n4 = n/4 float4 groups) ----------------
__global__ __launch_bounds__(256) void k_cvt(const float* __restrict__ in,
                                             u16* __restrict__ out, int n4) {
  int i = blockIdx.x * blockDim.x + threadIdx.x;
  if (i >= n4) return;
  float4 v = reinterpret_cast<const float4*>(in)[i];
  ushort4 o;
  o.x = f2bf(v.x); o.y = f2bf(v.y); o.z = f2bf(v.z); o.w = f2bf(v.w);
  reinterpret_cast<ushort4*>(out)[i] = o;
}

// ---------------- transpose f32 [K][N] -> bf16 [N][K] ----------------
__global__ __launch_bounds__(256) void k_transpose(const float* __restrict__ in,
                                                   u16* __restrict__ out, int K, int N) {
  __shared__ float tile[32][33];
  int n0 = blockIdx.x * 32, k0 = blockIdx.y * 32;
  int tx = threadIdx.x & 31, ty = threadIdx.x >> 5;  // 32 x 8
#pragma unroll
  for (int r = ty; r < 32; r += 8) tile[r][tx] = in[(long)(k0 + r) * N + n0 + tx];
  __syncthreads();
#pragma unroll
  for (int r = ty; r < 32; r += 8) out[(long)(n0 + r) * K + k0 + tx] = f2bf(tile[tx][r]);
}

// ---------------- QKV GEMM: 128x192 tile, BK=64, 4 waves, 8-phase, 2 blocks/CU ----------------
// XCD swizzle (T1): each XCD owns 128 consecutive wids = 4 B-panels (3MB, fits 4MB L2).
__global__ __launch_bounds__(256, 2) void k_gemm_qkv(const u16* __restrict__ A,
                                                     const u16* __restrict__ Bt,
                                                     const float* __restrict__ bias,
                                                     u16* __restrict__ Qb, u16* __restrict__ Kb,
                                                     u16* __restrict__ Vt) {
  constexpr int K = DM;        // 2048
  constexpr int NKT = K / 64;  // 32 K-tiles
  constexpr int NIT = NKT / 2; // 16 iterations
  __shared__ u16 LA[2 * 128 * 64];  // 32 KB
  __shared__ u16 LB[2 * 192 * 64];  // 48 KB
  int lin = blockIdx.y * 32 + blockIdx.x;   // 1024 blocks; HW round-robins XCD on lin
  int wid = (lin & 7) * 128 + (lin >> 3);   // bijective XCD chunking (1024 = 8*128)
  int m0 = (wid & 31) * 128;                // n-major decode: 4 n-panels per XCD
  int n0 = (wid >> 5) * 192;
  int t = threadIdx.x, lane = t & 63, w = t >> 6;
  int l15 = lane & 15, lhi = lane >> 4;
  int wrow = w >> 1, wcol = w & 1;  // 2x2 wave grid; per-wave out 64x96
  int srow = t >> 3;                       // 0..31
  int scol = ((t & 7) ^ (srow & 7)) * 8;

#define STG_A(TILE, IDX) do {                                                      \
    int kb_ = ((TILE) < NKT ? (TILE) : NKT - 1) * 64;                              \
    glds16(A + (long)(m0 + (IDX) * 32 + srow) * K + kb_ + scol,                    \
           LA + ((TILE) & 1) * 8192 + (IDX) * 2048 + w * 512);                     \
  } while (0)
#define STG_B(TILE, IDX) do {                                                      \
    int kb_ = ((TILE) < NKT ? (TILE) : NKT - 1) * 64;                              \
    glds16(Bt + (long)(n0 + (IDX) * 32 + srow) * K + kb_ + scol,                   \
           LB + ((TILE) & 1) * 12288 + (IDX) * 2048 + w * 512);                    \
  } while (0)

  bf16x8 af[2][2], bfr0[3][2], bfr1[3][2];
  f32x4 acc[4][6] = {};

#define LDA_FRAGS(BUF, QM) do {                                                    \
    _Pragma("unroll") for (int mi = 0; mi < 2; mi++) {                             \
      int rA = wrow * 64 + ((QM) * 2 + mi) * 16 + l15;                             \
      _Pragma("unroll") for (int kk = 0; kk < 2; kk++)                             \
        af[mi][kk] = *(const bf16x8*)(LA + (BUF) * 8192 + rA * 64 +                \
                                      (((kk * 4 + lhi) ^ (rA & 7)) * 8));          \
    } } while (0)
#define LDB_FRAGS(BUF, QN, DST) do {                                               \
    _Pragma("unroll") for (int ni = 0; ni < 3; ni++) {                             \
      int rB = wcol * 96 + ((QN) * 3 + ni) * 16 + l15;                             \
      _Pragma("unroll") for (int kk = 0; kk < 2; kk++)                             \
        DST[ni][kk] = *(const bf16x8*)(LB + (BUF) * 12288 + rB * 64 +              \
                                       (((kk * 4 + lhi) ^ (rB & 7)) * 8));         \
    } } while (0)
#define MM(QM, QN, BF) do {                                                        \
    __builtin_amdgcn_s_setprio(1);                                                 \
    _Pragma("unroll") for (int mi = 0; mi < 2; mi++)                               \
    _Pragma("unroll") for (int ni = 0; ni < 3; ni++)                               \
    _Pragma("unroll") for (int kk = 0; kk < 2; kk++)                               \
      acc[(QM) * 2 + mi][(QN) * 3 + ni] = __builtin_amdgcn_mfma_f32_16x16x32_bf16( \
          af[mi][kk], BF[ni][kk], acc[(QM) * 2 + mi][(QN) * 3 + ni], 0, 0, 0);     \
    __builtin_amdgcn_s_setprio(0);                                                 \
  } while (0)
#define BAR __builtin_amdgcn_s_barrier()
#define LG0 do { asm volatile("s_waitcnt lgkmcnt(0)" ::: "memory");                \
                 __builtin_amdgcn_sched_barrier(0); } while (0)
#define VMW6 do { asm volatile("s_waitcnt vmcnt(6)" ::: "memory");                 \
                  __builtin_amdgcn_sched_barrier(0); } while (0)

  STG_A(0, 0); STG_A(0, 1); STG_A(0, 2); STG_A(0, 3);
  STG_B(0, 0); STG_B(0, 1); STG_B(0, 2); STG_B(0, 3); STG_B(0, 4); STG_B(0, 5);
  STG_B(1, 0); STG_B(1, 1); STG_B(1, 2); STG_B(1, 3); STG_B(1, 4); STG_B(1, 5);
  VMW6; BAR;

  for (int it = 0; it < NIT; it++) {
    int k1 = 2 * it + 1, k2 = 2 * it + 2, k3 = 2 * it + 3;
    LDA_FRAGS(0, 0); LDB_FRAGS(0, 0, bfr0);
    STG_A(k1, 0); STG_A(k1, 1); STG_A(k1, 2);      BAR; LG0; MM(0, 0, bfr0); BAR;  // ph1
    LDB_FRAGS(0, 1, bfr1);
    STG_A(k1, 3);                                  BAR; LG0; MM(0, 1, bfr1); BAR;  // ph2
    LDA_FRAGS(0, 1);
    STG_B(k2, 0); STG_B(k2, 1); STG_B(k2, 2);      BAR; LG0; MM(1, 0, bfr0); BAR;  // ph3
    STG_B(k2, 3); STG_B(k2, 4); STG_B(k2, 5);
    VMW6;                                          BAR;      MM(1, 1, bfr1); BAR;  // ph4
    LDA_FRAGS(1, 0); LDB_FRAGS(1, 0, bfr0);
    STG_A(k2, 0); STG_A(k2, 1); STG_A(k2, 2);      BAR; LG0; MM(0, 0, bfr0); BAR;  // ph5
    LDB_FRAGS(1, 1, bfr1);
    STG_A(k2, 3);                                  BAR; LG0; MM(0, 1, bfr1); BAR;  // ph6
    LDA_FRAGS(1, 1);
    STG_B(k3, 0); STG_B(k3, 1); STG_B(k3, 2);      BAR; LG0; MM(1, 0, bfr0); BAR;  // ph7
    STG_B(k3, 3); STG_B(k3, 4); STG_B(k3, 5);
    VMW6;                                          BAR;      MM(1, 1, bfr1); BAR;  // ph8
  }
#undef STG_A
#undef STG_B
#undef LDA_FRAGS
#undef LDB_FRAGS
#undef MM
#undef BAR
#undef LG0
#undef VMW6

#pragma unroll
  for (int mi = 0; mi < 4; mi++)
#pragma unroll
    for (int ni = 0; ni < 6; ni++) {
      int col = n0 + wcol * 96 + ni * 16 + l15;
      float bv = bias[col];
      int sec = col >> 11, dn = col & 2047, h = dn >> 7, hd = dn & 127;
#pragma unroll
      for (int r = 0; r < 4; r++) {
        int row = m0 + wrow * 64 + mi * 16 + lhi * 4 + r;
        int bb = row >> 11, ss = row & 2047;
        u16 val = f2bf(acc[mi][ni][r] + bv);
        if (sec == 0)
          Qb[(((long)(bb * NH + h)) * SEQ + ss) * HD + hd] = val;
        else if (sec == 1)
          Kb[(((long)(bb * NH + h)) * SEQ + ss) * HD + hd] = val;
        else
          Vt[(((long)(bb * NH + h)) * HD + hd) * SEQ + ss] = val;
      }
    }
}

// ---------------- output GEMM: 128x128 tile, BK=64, 4 waves, 8-phase, 2 blocks/CU ----------------
// XCD swizzle: each XCD owns 64 consecutive wids = 2 B-panels (1MB) in its L2.
__global__ __launch_bounds__(256, 2) void k_gemm_out(const u16* __restrict__ A,
                                                     const u16* __restrict__ Bt,
                                                     const float* __restrict__ bias,
                                                     float* __restrict__ Out) {
  constexpr int K = DM, N = DM;
  constexpr int NKT = K / 64;  // 32
  constexpr int NIT = NKT / 2; // 16
  __shared__ u16 LA[2 * 128 * 64];  // 32 KB
  __shared__ u16 LB[2 * 128 * 64];  // 32 KB
  int lin = blockIdx.y * 16 + blockIdx.x;   // 512 blocks
  int wid = (lin & 7) * 64 + (lin >> 3);    // bijective (512 = 8*64)
  int m0 = (wid & 31) * 128;
  int n0 = (wid >> 5) * 128;
  int t = threadIdx.x, lane = t & 63, w = t >> 6;
  int l15 = lane & 15, lhi = lane >> 4;
  int wrow = w >> 1, wcol = w & 1;  // 2x2 waves; per-wave out 64x64
  int srow = t >> 3;                // 0..31
  int scol = ((t & 7) ^ (srow & 7)) * 8;

#define STG_A(TILE, IDX) do {                                                      \
    int kb_ = ((TILE) < NKT ? (TILE) : NKT - 1) * 64;                              \
    glds16(A + (long)(m0 + (IDX) * 32 + srow) * K + kb_ + scol,                    \
           LA + ((TILE) & 1) * 8192 + (IDX) * 2048 + w * 512);                     \
  } while (0)
#define STG_B(TILE, IDX) do {                                                      \
    int kb_ = ((TILE) < NKT ? (TILE) : NKT - 1) * 64;                              \
    glds16(Bt + (long)(n0 + (IDX) * 32 + srow) * K + kb_ + scol,                   \
           LB + ((TILE) & 1) * 8192 + (IDX) * 2048 + w * 512);                     \
  } while (0)

  bf16x8 af[2][2], bfr0[2][2], bfr1[2][2];
  f32x4 acc[4][4] = {};

#define LDA_FRAGS(BUF, QM) do {                                                    \
    _Pragma("unroll") for (int mi = 0; mi < 2; mi++) {                             \
      int rA = wrow * 64 + ((QM) * 2 + mi) * 16 + l15;                             \
      _Pragma("unroll") for (int kk = 0; kk < 2; kk++)                             \
        af[mi][kk] = *(const bf16x8*)(LA + (BUF) * 8192 + rA * 64 +                \
                                      (((kk * 4 + lhi) ^ (rA & 7)) * 8));          \
    } } while (0)
#define LDB_FRAGS(BUF, QN, DST) do {                                               \
    _Pragma("unroll") for (int ni = 0; ni < 2; ni++) {                             \
      int rB = wcol * 64 + ((QN) * 2 + ni) * 16 + l15;                             \
      _Pragma("unroll") for (int kk = 0; kk < 2; kk++)                             \
        DST[ni][kk] = *(const bf16x8*)(LB + (BUF) * 8192 + rB * 64 +               \
                                       (((kk * 4 + lhi) ^ (rB & 7)) * 8));         \
    } } while (0)
#define MM(QM, QN, BF) do {                                                        \
    __builtin_amdgcn_s_setprio(1);                                                 \
    _Pragma("unroll") for (int mi = 0; mi < 2; mi++)                               \
    _Pragma("unroll") for (int ni = 0; ni < 2; ni++)                               \
    _Pragma("unroll") for (int kk = 0; kk < 2; kk++)                               \
      acc[(QM) * 2 + mi][(QN) * 2 + ni] = __builtin_amdgcn_mfma_f32_16x16x32_bf16( \
          af[mi][kk], BF[ni][kk], acc[(QM) * 2 + mi][(QN) * 2 + ni], 0, 0, 0);     \
    __builtin_amdgcn_s_setprio(0);                                                 \
  } while (0)
#define BAR __builtin_amdgcn_s_barrier()
#define LG0 do { asm volatile("s_waitcnt lgkmcnt(0)" ::: "memory");                \
                 __builtin_amdgcn_sched_barrier(0); } while (0)
#define VMW4 do { asm volatile("s_waitcnt vmcnt(4)" ::: "memory");                 \
                  __builtin_amdgcn_sched_barrier(0); } while (0)

  STG_A(0, 0); STG_A(0, 1); STG_A(0, 2); STG_A(0, 3);
  STG_B(0, 0); STG_B(0, 1); STG_B(0, 2); STG_B(0, 3);
  STG_B(1, 0); STG_B(1, 1); STG_B(1, 2); STG_B(1, 3);
  VMW4; BAR;

  for (int it = 0; it < NIT; it++) {
    int k1 = 2 * it + 1, k2 = 2 * it + 2, k3 = 2 * it + 3;
    LDA_FRAGS(0, 0); LDB_FRAGS(0, 0, bfr0);
    STG_A(k1, 0); STG_A(k1, 1); STG_A(k1, 2);      BAR; LG0; MM(0, 0, bfr0); BAR;  // ph1
    LDB_FRAGS(0, 1, bfr1);
    STG_A(k1, 3);                                  BAR; LG0; MM(0, 1, bfr1); BAR;  // ph2
    LDA_FRAGS(0, 1);
    STG_B(k2, 0); STG_B(k2, 1); STG_B(k2, 2);      BAR; LG0; MM(1, 0, bfr0); BAR;  // ph3
    STG_B(k2, 3);
    VMW4;                                          BAR;      MM(1, 1, bfr1); BAR;  // ph4
    LDA_FRAGS(1, 0); LDB_FRAGS(1, 0, bfr0);
    STG_A(k2, 0); STG_A(k2, 1); STG_A(k2, 2);      BAR; LG0; MM(0, 0, bfr0); BAR;  // ph5
    LDB_FRAGS(1, 1, bfr1);
    STG_A(k2, 3);                                  BAR; LG0; MM(0, 1, bfr1); BAR;  // ph6
    LDA_FRAGS(1, 1);
    STG_B(k3, 0); STG_B(k3, 1); STG_B(k3, 2);      BAR; LG0; MM(1, 0, bfr0); BAR;  // ph7
    STG_B(k3, 3);
    VMW4;                                          BAR;      MM(1, 1, bfr1); BAR;  // ph8
  }
#undef STG_A
#undef STG_B
#undef LDA_FRAGS
#undef LDB_FRAGS
#undef MM
#undef BAR
#undef LG0
#undef VMW4

#pragma unroll
  for (int mi = 0; mi < 4; mi++)
#pragma unroll
    for (int ni = 0; ni < 4; ni++) {
      int col = n0 + wcol * 64 + ni * 16 + l15;
      float bv = bias[col];
#pragma unroll
      for (int r = 0; r < 4; r++) {
        int row = m0 + wrow * 64 + mi * 16 + lhi * 4 + r;
        Out[(long)row * N + col] = acc[mi][ni][r] + bv;
      }
    }
}

// ---------------- flash attention (causal + alibi), load-balanced, XCD-chunked ----------------
// Each XCD owns 64 consecutive wids = 4 heads -> K/V (~4MB) resident in its L2.
__global__ __launch_bounds__(256) void k_attn(const u16* __restrict__ Qb,
                                              const u16* __restrict__ Kb,
                                              const u16* __restrict__ Vt,
                                              const float* __restrict__ mask,
                                              u16* __restrict__ Ao) {
  constexpr int NT = SEQ / 64;  // 32
  int lin = blockIdx.y * gridDim.x + blockIdx.x;  // 512 blocks
  int wid = (lin & 7) * 64 + (lin >> 3);          // bijective (512 = 8*64)
  int bh = wid >> 4;            // 4 heads per XCD chunk
  int qp = wid & 15;
  int t = threadIdx.x, w = t >> 6, lane = t & 63;
  int l15 = lane & 15, lhi = lane >> 4;
  int b = bh >> 4, h = bh & 15;
  const u16* Qh = Qb + (long)bh * SEQ * HD;
  const u16* Kh = Kb + (long)bh * SEQ * HD;
  const u16* Vh = Vt + (long)bh * HD * SEQ;
  const float* mh = mask + h * SEQ;

  __shared__ u16 Ks[64 * 128];
  __shared__ u16 Vs[128 * 64];
  __shared__ u16 p_lds[4 * 16 * 64];
  u16* pw = p_lds + w * (16 * 64);

  int krow[4], kcol[4], vrow[4], vcol[4];
#pragma unroll
  for (int i = 0; i < 4; i++) {
    int c = i * 256 + t;
    krow[i] = c >> 4; kcol[i] = (c & 15) * 8;   // K: 64 rows x 128 elems
    vrow[i] = c >> 3; vcol[i] = (c & 7) * 8;    // V: 128 rows x 64 elems
  }

  const float sm_scale = 0.08838834764831845f;  // 1/sqrt(128)

  for (int half = 0; half < 2; half++) {
    int qt = half ? qp : (NT - 1 - qp);  // long half first
    int q0 = qt * 64 + w * 16;
    int nt = qt + 1;

    bf16x8 qf[4];
#pragma unroll
    for (int kc = 0; kc < 4; kc++)
      qf[kc] = *(const bf16x8*)(Qh + (long)(q0 + l15) * HD + kc * 32 + lhi * 8);

    int rowr[4];
#pragma unroll
    for (int r = 0; r < 4; r++) rowr[r] = q0 + lhi * 4 + r;

    float mrun[4], lrun[4];
    f32x4 oacc[8] = {};
#pragma unroll
    for (int r = 0; r < 4; r++) { mrun[r] = -1e30f; lrun[r] = 0.f; }

    bf16x8 kst[4], vst[4];
#pragma unroll
    for (int i = 0; i < 4; i++) kst[i] = *(const bf16x8*)(Kh + (long)krow[i] * HD + kcol[i]);
#pragma unroll
    for (int i = 0; i < 4; i++) vst[i] = *(const bf16x8*)(Vh + (long)vrow[i] * SEQ + vcol[i]);
    __syncthreads();
#pragma unroll
    for (int i = 0; i < 4; i++)
      *(bf16x8*)(Ks + krow[i] * 128 + (kcol[i] ^ ((krow[i] & 7) << 3))) = kst[i];
#pragma unroll
    for (int i = 0; i < 4; i++)
      *(bf16x8*)(Vs + vrow[i] * 64 + (vcol[i] ^ ((vrow[i] & 7) << 3))) = vst[i];
    __syncthreads();

    for (int kt = 0; kt < nt; kt++) {
      int kb = kt * 64;
      bool have_next = (kt + 1 < nt);
      bool diag = (kt == nt - 1);
      if (have_next) {
        int kb2 = kb + 64;
#pragma unroll
        for (int i = 0; i < 4; i++)
          kst[i] = *(const bf16x8*)(Kh + (long)(kb2 + krow[i]) * HD + kcol[i]);
#pragma unroll
        for (int i = 0; i < 4; i++)
          vst[i] = *(const bf16x8*)(Vh + (long)vrow[i] * SEQ + kb2 + vcol[i]);
      }
      float bvv[4];
#pragma unroll
      for (int cb = 0; cb < 4; cb++) bvv[cb] = mh[kb + cb * 16 + l15];
      f32x4 sc[4] = {};
      __builtin_amdgcn_s_setprio(1);
#pragma unroll
      for (int kc = 0; kc < 4; kc++)
#pragma unroll
        for (int cb = 0; cb < 4; cb++) {
          int rr = cb * 16 + l15;
          bf16x8 kf = *(const bf16x8*)(Ks + rr * 128 + ((kc * 32 + lhi * 8) ^ ((rr & 7) << 3)));
          sc[cb] = __builtin_amdgcn_mfma_f32_16x16x32_bf16(qf[kc], kf, sc[cb], 0, 0, 0);
        }
      __builtin_amdgcn_s_setprio(0);
      float p[4][4], tmax[4];
#pragma unroll
      for (int cb = 0; cb < 4; cb++) {
        int col = kb + cb * 16 + l15;
#pragma unroll
        for (int r = 0; r < 4; r++) {
          float v = sc[cb][r] * sm_scale + bvv[cb];
          if (diag) v = (col <= rowr[r]) ? v : -1e30f;
          p[cb][r] = v;
        }
      }
#pragma unroll
      for (int r = 0; r < 4; r++)
        tmax[r] = fmaxf(fmaxf(p[0][r], p[1][r]), fmaxf(p[2][r], p[3][r]));
      float alpha[4];
#pragma unroll
      for (int r = 0; r < 4; r++) {
        float v = tmax[r];
        v = fmaxf(v, __shfl_xor(v, 1));
        v = fmaxf(v, __shfl_xor(v, 2));
        v = fmaxf(v, __shfl_xor(v, 4));
        v = fmaxf(v, __shfl_xor(v, 8));
        float mnew = fmaxf(mrun[r], v);
        alpha[r] = __expf(mrun[r] - mnew);
        mrun[r] = mnew;
        float s = 0.f;
#pragma unroll
        for (int cb = 0; cb < 4; cb++) {
          float e = __expf(p[cb][r] - mnew);
          p[cb][r] = e;
          s += e;
        }
        s += __shfl_xor(s, 1); s += __shfl_xor(s, 2);
        s += __shfl_xor(s, 4); s += __shfl_xor(s, 8);
        lrun[r] = lrun[r] * alpha[r] + s;
      }
#pragma unroll
      for (int nb = 0; nb < 8; nb++)
#pragma unroll
        for (int r = 0; r < 4; r++) oacc[nb][r] *= alpha[r];
#pragma unroll
      for (int cb = 0; cb < 4; cb++)
#pragma unroll
        for (int r = 0; r < 4; r++) {
          int rr = lhi * 4 + r;
          pw[(rr * 64 + cb * 16 + l15) ^ ((rr & 7) << 3)] = f2bf(p[cb][r]);
        }
      asm volatile("s_waitcnt lgkmcnt(0)" ::: "memory");
      bf16x8 pa0 = *(const bf16x8*)(pw + ((l15 * 64 + lhi * 8) ^ ((l15 & 7) << 3)));
      bf16x8 pa1 = *(const bf16x8*)(pw + ((l15 * 64 + 32 + lhi * 8) ^ ((l15 & 7) << 3)));
      __builtin_amdgcn_s_setprio(1);
#pragma unroll
      for (int nb = 0; nb < 8; nb++) {
        int rr = nb * 16 + l15;
        bf16x8 vf0 = *(const bf16x8*)(Vs + rr * 64 + ((lhi * 8) ^ ((rr & 7) << 3)));
        bf16x8 vf1 = *(const bf16x8*)(Vs + rr * 64 + ((32 + lhi * 8) ^ ((rr & 7) << 3)));
        oacc[nb] = __builtin_amdgcn_mfma_f32_16x16x32_bf16(pa0, vf0, oacc[nb], 0, 0, 0);
        oacc[nb] = __builtin_amdgcn_mfma_f32_16x16x32_bf16(pa1, vf1, oacc[nb], 0, 0, 0);
      }
      __builtin_amdgcn_s_setprio(0);
      if (have_next) {
        __syncthreads();
#pragma unroll
        for (int i = 0; i < 4; i++)
          *(bf16x8*)(Ks + krow[i] * 128 + (kcol[i] ^ ((krow[i] & 7) << 3))) = kst[i];
#pragma unroll
        for (int i = 0; i < 4; i++)
          *(bf16x8*)(Vs + vrow[i] * 64 + (vcol[i] ^ ((vrow[i] & 7) << 3))) = vst[i];
        __syncthreads();
      }
    }
#pragma unroll
    for (int nb = 0; nb < 8; nb++)
#pragma unroll
      for (int r = 0; r < 4; r++) {
        int row = q0 + lhi * 4 + r;
        float v = oacc[nb][r] / lrun[r];
        Ao[((long)(b * SEQ + row)) * DM + h * HD + nb * 16 + l15] = f2bf(v);
      }
  }
}

// ---------------- launcher ----------------
extern "C" void kernel_launch(void* const* d_in, const int* in_sizes, int n_in,
                              void* d_out, int out_size, void* d_ws, size_t ws_size,
                              hipStream_t stream) {
  const float* x    = (const float*)d_in[0];
  const float* amsk = (const float*)d_in[1];
  const float* Wqkv = (const float*)d_in[2];
  const float* bqkv = (const float*)d_in[3];
  const float* Wout = (const float*)d_in[4];
  const float* bout = (const float*)d_in[5];
  float* out = (float*)d_out;

  char* ws = (char*)d_ws;
  u16* xb  = (u16*)(ws + 0);                   // [4096][2048]
  u16* WqT = (u16*)(ws + 16777216UL);          // [6144][2048]
  u16* WoT = (u16*)(ws + 41943040UL);          // [2048][2048]
  u16* Qb  = (u16*)(ws + 50331648UL);          // [B*H][S][HD]
  u16* Kb  = (u16*)(ws + 67108864UL);          // [B*H][S][HD]
  u16* Vt  = (u16*)(ws + 83886080UL);          // [B*H][HD][S]
  u16* Ao  = (u16*)(ws + 100663296UL);         // [4096][2048]

  k_cvt<<<8192, 256, 0, stream>>>(x, xb, (MROWS * DM) / 4);
  k_transpose<<<dim3(N3 / 32, DM / 32), 256, 0, stream>>>(Wqkv, WqT, DM, N3);
  k_transpose<<<dim3(DM / 32, DM / 32), 256, 0, stream>>>(Wout, WoT, DM, DM);
  k_gemm_qkv<<<dim3(32, 32), 256, 0, stream>>>(xb, WqT, bqkv, Qb, Kb, Vt);
  k_attn<<<dim3(SEQ / 128, BATCH * NH), 256, 0, stream>>>(Qb, Kb, Vt, amsk, Ao);
  k_gemm_out<<<dim3(16, 32), 256, 0, stream>>>(Ao, WoT, bout, out);
}

// Round 13
// 294.631 us; speedup vs baseline: 1.1535x; 1.1535x over previous
//
#include <hip/hip_runtime.h>
#include <hip/hip_bf16.h>

typedef __bf16 bf16x8 __attribute__((ext_vector_type(8)));
typedef float f32x4 __attribute__((ext_vector_type(4)));
typedef unsigned short u16;

constexpr int BATCH = 2, SEQ = 2048, DM = 2048, NH = 16, HD = 128;
constexpr int N3 = 3 * DM;          // 6144
constexpr int MROWS = BATCH * SEQ;  // 4096

__device__ __forceinline__ u16 f2bf(float f) {
  unsigned u = __builtin_bit_cast(unsigned, f);
  unsigned r = 0x7FFFu + ((u >> 16) & 1u);
  return (u16)((u + r) >> 16);
}

// async global->LDS, 16B per lane; LDS dest = wave-uniform base + lane*16
__device__ __forceinline__ void glds16(const u16* g, u16* l) {
  __builtin_amdgcn_global_load_lds(
      (const __attribute__((address_space(1))) unsigned*)(const void*)g,
      (__attribute__((address_space(3))) unsigned*)(void*)l, 16, 0, 0);
}

// ---------------- convert f32 -> bf16 (n4 = n/4 float4 groups) ----------------
__global__ __launch_bounds__(256) void k_cvt(const float* __restrict__ in,
                                             u16* __restrict__ out, int n4) {
  int i = blockIdx.x * blockDim.x + threadIdx.x;
  if (i >= n4) return;
  float4 v = reinterpret_cast<const float4*>(in)[i];
  ushort4 o;
  o.x = f2bf(v.x); o.y = f2bf(v.y); o.z = f2bf(v.z); o.w = f2bf(v.w);
  reinterpret_cast<ushort4*>(out)[i] = o;
}

// ---------------- transpose f32 [K][N] -> bf16 [N][K] ----------------
__global__ __launch_bounds__(256) void k_transpose(const float* __restrict__ in,
                                                   u16* __restrict__ out, int K, int N) {
  __shared__ float tile[32][33];
  int n0 = blockIdx.x * 32, k0 = blockIdx.y * 32;
  int tx = threadIdx.x & 31, ty = threadIdx.x >> 5;  // 32 x 8
#pragma unroll
  for (int r = ty; r < 32; r += 8) tile[r][tx] = in[(long)(k0 + r) * N + n0 + tx];
  __syncthreads();
#pragma unroll
  for (int r = ty; r < 32; r += 8) out[(long)(n0 + r) * K + k0 + tx] = f2bf(tile[tx][r]);
}

// ---------------- QKV GEMM: 128x192 tile, BK=64, 4 waves, 8-phase, 2 blocks/CU ----------------
__global__ __launch_bounds__(256, 2) void k_gemm_qkv(const u16* __restrict__ A,
                                                     const u16* __restrict__ Bt,
                                                     const float* __restrict__ bias,
                                                     u16* __restrict__ Qb, u16* __restrict__ Kb,
                                                     u16* __restrict__ Vt) {
  constexpr int K = DM;        // 2048
  constexpr int NKT = K / 64;  // 32 K-tiles
  constexpr int NIT = NKT / 2; // 16 iterations
  __shared__ u16 LA[2 * 128 * 64];  // 32 KB
  __shared__ u16 LB[2 * 192 * 64];  // 48 KB
  int lin = blockIdx.y * 32 + blockIdx.x;
  int wid = (lin & 7) * 128 + (lin >> 3);
  int m0 = (wid & 31) * 128;
  int n0 = (wid >> 5) * 192;
  int t = threadIdx.x, lane = t & 63, w = t >> 6;
  int l15 = lane & 15, lhi = lane >> 4;
  int wrow = w >> 1, wcol = w & 1;  // 2x2 wave grid; per-wave out 64x96
  int srow = t >> 3;                       // 0..31
  int scol = ((t & 7) ^ (srow & 7)) * 8;

#define STG_A(TILE, IDX) do {                                                      \
    int kb_ = ((TILE) < NKT ? (TILE) : NKT - 1) * 64;                              \
    glds16(A + (long)(m0 + (IDX) * 32 + srow) * K + kb_ + scol,                    \
           LA + ((TILE) & 1) * 8192 + (IDX) * 2048 + w * 512);                     \
  } while (0)
#define STG_B(TILE, IDX) do {                                                      \
    int kb_ = ((TILE) < NKT ? (TILE) : NKT - 1) * 64;                              \
    glds16(Bt + (long)(n0 + (IDX) * 32 + srow) * K + kb_ + scol,                   \
           LB + ((TILE) & 1) * 12288 + (IDX) * 2048 + w * 512);                    \
  } while (0)

  bf16x8 af[2][2], bfr0[3][2], bfr1[3][2];
  f32x4 acc[4][6] = {};

#define LDA_FRAGS(BUF, QM) do {                                                    \
    _Pragma("unroll") for (int mi = 0; mi < 2; mi++) {                             \
      int rA = wrow * 64 + ((QM) * 2 + mi) * 16 + l15;                             \
      _Pragma("unroll") for (int kk = 0; kk < 2; kk++)                             \
        af[mi][kk] = *(const bf16x8*)(LA + (BUF) * 8192 + rA * 64 +                \
                                      (((kk * 4 + lhi) ^ (rA & 7)) * 8));          \
    } } while (0)
#define LDB_FRAGS(BUF, QN, DST) do {                                               \
    _Pragma("unroll") for (int ni = 0; ni < 3; ni++) {                             \
      int rB = wcol * 96 + ((QN) * 3 + ni) * 16 + l15;                             \
      _Pragma("unroll") for (int kk = 0; kk < 2; kk++)                             \
        DST[ni][kk] = *(const bf16x8*)(LB + (BUF) * 12288 + rB * 64 +              \
                                       (((kk * 4 + lhi) ^ (rB & 7)) * 8));         \
    } } while (0)
#define MM(QM, QN, BF) do {                                                        \
    __builtin_amdgcn_s_setprio(1);                                                 \
    _Pragma("unroll") for (int mi = 0; mi < 2; mi++)                               \
    _Pragma("unroll") for (int ni = 0; ni < 3; ni++)                               \
    _Pragma("unroll") for (int kk = 0; kk < 2; kk++)                               \
      acc[(QM) * 2 + mi][(QN) * 3 + ni] = __builtin_amdgcn_mfma_f32_16x16x32_bf16( \
          af[mi][kk], BF[ni][kk], acc[(QM) * 2 + mi][(QN) * 3 + ni], 0, 0, 0);     \
    __builtin_amdgcn_s_setprio(0);                                                 \
  } while (0)
#define BAR __builtin_amdgcn_s_barrier()
#define LG0 do { asm volatile("s_waitcnt lgkmcnt(0)" ::: "memory");                \
                 __builtin_amdgcn_sched_barrier(0); } while (0)
#define VMW6 do { asm volatile("s_waitcnt vmcnt(6)" ::: "memory");                 \
                  __builtin_amdgcn_sched_barrier(0); } while (0)

  STG_A(0, 0); STG_A(0, 1); STG_A(0, 2); STG_A(0, 3);
  STG_B(0, 0); STG_B(0, 1); STG_B(0, 2); STG_B(0, 3); STG_B(0, 4); STG_B(0, 5);
  STG_B(1, 0); STG_B(1, 1); STG_B(1, 2); STG_B(1, 3); STG_B(1, 4); STG_B(1, 5);
  VMW6; BAR;

  for (int it = 0; it < NIT; it++) {
    int k1 = 2 * it + 1, k2 = 2 * it + 2, k3 = 2 * it + 3;
    LDA_FRAGS(0, 0); LDB_FRAGS(0, 0, bfr0);
    STG_A(k1, 0); STG_A(k1, 1); STG_A(k1, 2);      BAR; LG0; MM(0, 0, bfr0); BAR;  // ph1
    LDB_FRAGS(0, 1, bfr1);
    STG_A(k1, 3);                                  BAR; LG0; MM(0, 1, bfr1); BAR;  // ph2
    LDA_FRAGS(0, 1);
    STG_B(k2, 0); STG_B(k2, 1); STG_B(k2, 2);      BAR; LG0; MM(1, 0, bfr0); BAR;  // ph3
    STG_B(k2, 3); STG_B(k2, 4); STG_B(k2, 5);
    VMW6;                                          BAR;      MM(1, 1, bfr1); BAR;  // ph4
    LDA_FRAGS(1, 0); LDB_FRAGS(1, 0, bfr0);
    STG_A(k2, 0); STG_A(k2, 1); STG_A(k2, 2);      BAR; LG0; MM(0, 0, bfr0); BAR;  // ph5
    LDB_FRAGS(1, 1, bfr1);
    STG_A(k2, 3);                                  BAR; LG0; MM(0, 1, bfr1); BAR;  // ph6
    LDA_FRAGS(1, 1);
    STG_B(k3, 0); STG_B(k3, 1); STG_B(k3, 2);      BAR; LG0; MM(1, 0, bfr0); BAR;  // ph7
    STG_B(k3, 3); STG_B(k3, 4); STG_B(k3, 5);
    VMW6;                                          BAR;      MM(1, 1, bfr1); BAR;  // ph8
  }
#undef STG_A
#undef STG_B
#undef LDA_FRAGS
#undef LDB_FRAGS
#undef MM
#undef BAR
#undef LG0
#undef VMW6

#pragma unroll
  for (int mi = 0; mi < 4; mi++)
#pragma unroll
    for (int ni = 0; ni < 6; ni++) {
      int col = n0 + wcol * 96 + ni * 16 + l15;
      float bv = bias[col];
      int sec = col >> 11, dn = col & 2047, h = dn >> 7, hd = dn & 127;
#pragma unroll
      for (int r = 0; r < 4; r++) {
        int row = m0 + wrow * 64 + mi * 16 + lhi * 4 + r;
        int bb = row >> 11, ss = row & 2047;
        u16 val = f2bf(acc[mi][ni][r] + bv);
        if (sec == 0)
          Qb[(((long)(bb * NH + h)) * SEQ + ss) * HD + hd] = val;
        else if (sec == 1)
          Kb[(((long)(bb * NH + h)) * SEQ + ss) * HD + hd] = val;
        else
          Vt[(((long)(bb * NH + h)) * HD + hd) * SEQ + ss] = val;
      }
    }
}

// ---------------- output GEMM: 128x128 tile, BK=64, 4 waves, 8-phase, 2 blocks/CU ----------------
__global__ __launch_bounds__(256, 2) void k_gemm_out(const u16* __restrict__ A,
                                                     const u16* __restrict__ Bt,
                                                     const float* __restrict__ bias,
                                                     float* __restrict__ Out) {
  constexpr int K = DM, N = DM;
  constexpr int NKT = K / 64;  // 32
  constexpr int NIT = NKT / 2; // 16
  __shared__ u16 LA[2 * 128 * 64];  // 32 KB
  __shared__ u16 LB[2 * 128 * 64];  // 32 KB
  int lin = blockIdx.y * 16 + blockIdx.x;
  int wid = (lin & 7) * 64 + (lin >> 3);
  int m0 = (wid & 31) * 128;
  int n0 = (wid >> 5) * 128;
  int t = threadIdx.x, lane = t & 63, w = t >> 6;
  int l15 = lane & 15, lhi = lane >> 4;
  int wrow = w >> 1, wcol = w & 1;  // 2x2 waves; per-wave out 64x64
  int srow = t >> 3;                // 0..31
  int scol = ((t & 7) ^ (srow & 7)) * 8;

#define STG_A(TILE, IDX) do {                                                      \
    int kb_ = ((TILE) < NKT ? (TILE) : NKT - 1) * 64;                              \
    glds16(A + (long)(m0 + (IDX) * 32 + srow) * K + kb_ + scol,                    \
           LA + ((TILE) & 1) * 8192 + (IDX) * 2048 + w * 512);                     \
  } while (0)
#define STG_B(TILE, IDX) do {                                                      \
    int kb_ = ((TILE) < NKT ? (TILE) : NKT - 1) * 64;                              \
    glds16(Bt + (long)(n0 + (IDX) * 32 + srow) * K + kb_ + scol,                   \
           LB + ((TILE) & 1) * 8192 + (IDX) * 2048 + w * 512);                     \
  } while (0)

  bf16x8 af[2][2], bfr0[2][2], bfr1[2][2];
  f32x4 acc[4][4] = {};

#define LDA_FRAGS(BUF, QM) do {                                                    \
    _Pragma("unroll") for (int mi = 0; mi < 2; mi++) {                             \
      int rA = wrow * 64 + ((QM) * 2 + mi) * 16 + l15;                             \
      _Pragma("unroll") for (int kk = 0; kk < 2; kk++)                             \
        af[mi][kk] = *(const bf16x8*)(LA + (BUF) * 8192 + rA * 64 +                \
                                      (((kk * 4 + lhi) ^ (rA & 7)) * 8));          \
    } } while (0)
#define LDB_FRAGS(BUF, QN, DST) do {                                               \
    _Pragma("unroll") for (int ni = 0; ni < 2; ni++) {                             \
      int rB = wcol * 64 + ((QN) * 2 + ni) * 16 + l15;                             \
      _Pragma("unroll") for (int kk = 0; kk < 2; kk++)                             \
        DST[ni][kk] = *(const bf16x8*)(LB + (BUF) * 8192 + rB * 64 +               \
                                       (((kk * 4 + lhi) ^ (rB & 7)) * 8));         \
    } } while (0)
#define MM(QM, QN, BF) do {                                                        \
    __builtin_amdgcn_s_setprio(1);                                                 \
    _Pragma("unroll") for (int mi = 0; mi < 2; mi++)                               \
    _Pragma("unroll") for (int ni = 0; ni < 2; ni++)                               \
    _Pragma("unroll") for (int kk = 0; kk < 2; kk++)                               \
      acc[(QM) * 2 + mi][(QN) * 2 + ni] = __builtin_amdgcn_mfma_f32_16x16x32_bf16( \
          af[mi][kk], BF[ni][kk], acc[(QM) * 2 + mi][(QN) * 2 + ni], 0, 0, 0);     \
    __builtin_amdgcn_s_setprio(0);                                                 \
  } while (0)
#define BAR __builtin_amdgcn_s_barrier()
#define LG0 do { asm volatile("s_waitcnt lgkmcnt(0)" ::: "memory");                \
                 __builtin_amdgcn_sched_barrier(0); } while (0)
#define VMW4 do { asm volatile("s_waitcnt vmcnt(4)" ::: "memory");                 \
                  __builtin_amdgcn_sched_barrier(0); } while (0)

  STG_A(0, 0); STG_A(0, 1); STG_A(0, 2); STG_A(0, 3);
  STG_B(0, 0); STG_B(0, 1); STG_B(0, 2); STG_B(0, 3);
  STG_B(1, 0); STG_B(1, 1); STG_B(1, 2); STG_B(1, 3);
  VMW4; BAR;

  for (int it = 0; it < NIT; it++) {
    int k1 = 2 * it + 1, k2 = 2 * it + 2, k3 = 2 * it + 3;
    LDA_FRAGS(0, 0); LDB_FRAGS(0, 0, bfr0);
    STG_A(k1, 0); STG_A(k1, 1); STG_A(k1, 2);      BAR; LG0; MM(0, 0, bfr0); BAR;  // ph1
    LDB_FRAGS(0, 1, bfr1);
    STG_A(k1, 3);                                  BAR; LG0; MM(0, 1, bfr1); BAR;  // ph2
    LDA_FRAGS(0, 1);
    STG_B(k2, 0); STG_B(k2, 1); STG_B(k2, 2);      BAR; LG0; MM(1, 0, bfr0); BAR;  // ph3
    STG_B(k2, 3);
    VMW4;                                          BAR;      MM(1, 1, bfr1); BAR;  // ph4
    LDA_FRAGS(1, 0); LDB_FRAGS(1, 0, bfr0);
    STG_A(k2, 0); STG_A(k2, 1); STG_A(k2, 2);      BAR; LG0; MM(0, 0, bfr0); BAR;  // ph5
    LDB_FRAGS(1, 1, bfr1);
    STG_A(k2, 3);                                  BAR; LG0; MM(0, 1, bfr1); BAR;  // ph6
    LDA_FRAGS(1, 1);
    STG_B(k3, 0); STG_B(k3, 1); STG_B(k3, 2);      BAR; LG0; MM(1, 0, bfr0); BAR;  // ph7
    STG_B(k3, 3);
    VMW4;                                          BAR;      MM(1, 1, bfr1); BAR;  // ph8
  }
#undef STG_A
#undef STG_B
#undef LDA_FRAGS
#undef LDB_FRAGS
#undef MM
#undef BAR
#undef LG0
#undef VMW4

#pragma unroll
  for (int mi = 0; mi < 4; mi++)
#pragma unroll
    for (int ni = 0; ni < 4; ni++) {
      int col = n0 + wcol * 64 + ni * 16 + l15;
      float bv = bias[col];
#pragma unroll
      for (int r = 0; r < 4; r++) {
        int row = m0 + wrow * 64 + mi * 16 + lhi * 4 + r;
        Out[(long)row * N + col] = acc[mi][ni][r] + bv;
      }
    }
}

// ---------------- flash attention: glds16 async double-buffered K/V, 1 barrier/tile ----------------
// Grid mapping reverted to R10 (XCD swizzle falsified in R12: FETCH -5x but dur +53us).
// Staging: 8x global_load_lds per tile into buf cur^1, issued at iter top; the single
// __syncthreads() per iter (implicit vmcnt drain) guarantees completion for iter+1.
__global__ __launch_bounds__(256) void k_attn(const u16* __restrict__ Qb,
                                              const u16* __restrict__ Kb,
                                              const u16* __restrict__ Vt,
                                              const float* __restrict__ mask,
                                              u16* __restrict__ Ao) {
  constexpr int NT = SEQ / 64;  // 32
  int bh = blockIdx.y;          // b*NH + h
  int qp = blockIdx.x;          // 0..NT/2-1
  int t = threadIdx.x, w = t >> 6, lane = t & 63;
  int l15 = lane & 15, lhi = lane >> 4;
  int b = bh >> 4, h = bh & 15;
  const u16* Qh = Qb + (long)bh * SEQ * HD;
  const u16* Kh = Kb + (long)bh * SEQ * HD;
  const u16* Vh = Vt + (long)bh * HD * SEQ;
  const float* mh = mask + h * SEQ;

  __shared__ u16 Ks[2][64 * 128];   // 32 KB
  __shared__ u16 Vs[2][128 * 64];   // 32 KB
  __shared__ u16 p_lds[4 * 16 * 64];
  u16* pw = p_lds + w * (16 * 64);

  // staging source coords (chunk c = i*256+t; source col pre-swizzled; LDS dest linear)
  int krow[4], kcolS[4], vrow[4], vcolS[4];
#pragma unroll
  for (int i = 0; i < 4; i++) {
    int c = i * 256 + t;
    krow[i] = c >> 4; kcolS[i] = ((c & 15) ^ ((c >> 4) & 7)) * 8;   // K: 64 x 128
    vrow[i] = c >> 3; vcolS[i] = ((c & 7) ^ ((c >> 3) & 7)) * 8;    // V: 128 x 64
  }

#define STAGE(KT, BUF) do {                                                        \
    int kb_ = (KT) * 64;                                                           \
    _Pragma("unroll") for (int i = 0; i < 4; i++)                                  \
      glds16(Kh + (long)(kb_ + krow[i]) * HD + kcolS[i],                           \
             &Ks[BUF][(i * 256 + w * 64) * 8]);                                    \
    _Pragma("unroll") for (int i = 0; i < 4; i++)                                  \
      glds16(Vh + (long)vrow[i] * SEQ + kb_ + vcolS[i],                            \
             &Vs[BUF][(i * 256 + w * 64) * 8]);                                    \
  } while (0)

  const float sm_scale = 0.08838834764831845f;  // 1/sqrt(128)

  for (int half = 0; half < 2; half++) {
    int qt = half ? qp : (NT - 1 - qp);  // long half first
    int q0 = qt * 64 + w * 16;
    int nt = qt + 1;

    bf16x8 qf[4];
#pragma unroll
    for (int kc = 0; kc < 4; kc++)
      qf[kc] = *(const bf16x8*)(Qh + (long)(q0 + l15) * HD + kc * 32 + lhi * 8);

    int rowr[4];
#pragma unroll
    for (int r = 0; r < 4; r++) rowr[r] = q0 + lhi * 4 + r;

    float mrun[4], lrun[4];
    f32x4 oacc[8] = {};
#pragma unroll
    for (int r = 0; r < 4; r++) { mrun[r] = -1e30f; lrun[r] = 0.f; }

    STAGE(0, 0);
    __syncthreads();  // drains vmcnt: tile 0 resident; also fences prior half's reads

    for (int kt = 0; kt < nt; kt++) {
      int cur = kt & 1;
      if (kt + 1 < nt) STAGE(kt + 1, cur ^ 1);  // async into other buffer
      bool diag = (kt == nt - 1);
      int kb = kt * 64;
      const u16* Ksg = Ks[cur];
      const u16* Vsg = Vs[cur];
      float bvv[4];
#pragma unroll
      for (int cb = 0; cb < 4; cb++) bvv[cb] = mh[kb + cb * 16 + l15];
      f32x4 sc[4] = {};
      __builtin_amdgcn_s_setprio(1);
#pragma unroll
      for (int kc = 0; kc < 4; kc++)
#pragma unroll
        for (int cb = 0; cb < 4; cb++) {
          int rr = cb * 16 + l15;
          bf16x8 kf = *(const bf16x8*)(Ksg + rr * 128 + ((kc * 32 + lhi * 8) ^ ((rr & 7) << 3)));
          sc[cb] = __builtin_amdgcn_mfma_f32_16x16x32_bf16(qf[kc], kf, sc[cb], 0, 0, 0);
        }
      __builtin_amdgcn_s_setprio(0);
      float p[4][4], tmax[4];
#pragma unroll
      for (int cb = 0; cb < 4; cb++) {
        int col = kb + cb * 16 + l15;
#pragma unroll
        for (int r = 0; r < 4; r++) {
          float v = sc[cb][r] * sm_scale + bvv[cb];
          if (diag) v = (col <= rowr[r]) ? v : -1e30f;
          p[cb][r] = v;
        }
      }
#pragma unroll
      for (int r = 0; r < 4; r++)
        tmax[r] = fmaxf(fmaxf(p[0][r], p[1][r]), fmaxf(p[2][r], p[3][r]));
      float alpha[4];
#pragma unroll
      for (int r = 0; r < 4; r++) {
        float v = tmax[r];
        v = fmaxf(v, __shfl_xor(v, 1));
        v = fmaxf(v, __shfl_xor(v, 2));
        v = fmaxf(v, __shfl_xor(v, 4));
        v = fmaxf(v, __shfl_xor(v, 8));
        float mnew = fmaxf(mrun[r], v);
        alpha[r] = __expf(mrun[r] - mnew);
        mrun[r] = mnew;
        float s = 0.f;
#pragma unroll
        for (int cb = 0; cb < 4; cb++) {
          float e = __expf(p[cb][r] - mnew);
          p[cb][r] = e;
          s += e;
        }
        s += __shfl_xor(s, 1); s += __shfl_xor(s, 2);
        s += __shfl_xor(s, 4); s += __shfl_xor(s, 8);
        lrun[r] = lrun[r] * alpha[r] + s;
      }
#pragma unroll
      for (int nb = 0; nb < 8; nb++)
#pragma unroll
        for (int r = 0; r < 4; r++) oacc[nb][r] *= alpha[r];
#pragma unroll
      for (int cb = 0; cb < 4; cb++)
#pragma unroll
        for (int r = 0; r < 4; r++) {
          int rr = lhi * 4 + r;
          pw[(rr * 64 + cb * 16 + l15) ^ ((rr & 7) << 3)] = f2bf(p[cb][r]);
        }
      asm volatile("s_waitcnt lgkmcnt(0)" ::: "memory");
      bf16x8 pa0 = *(const bf16x8*)(pw + ((l15 * 64 + lhi * 8) ^ ((l15 & 7) << 3)));
      bf16x8 pa1 = *(const bf16x8*)(pw + ((l15 * 64 + 32 + lhi * 8) ^ ((l15 & 7) << 3)));
      __builtin_amdgcn_s_setprio(1);
#pragma unroll
      for (int nb = 0; nb < 8; nb++) {
        int rr = nb * 16 + l15;
        bf16x8 vf0 = *(const bf16x8*)(Vsg + rr * 64 + ((lhi * 8) ^ ((rr & 7) << 3)));
        bf16x8 vf1 = *(const bf16x8*)(Vsg + rr * 64 + ((32 + lhi * 8) ^ ((rr & 7) << 3)));
        oacc[nb] = __builtin_amdgcn_mfma_f32_16x16x32_bf16(pa0, vf0, oacc[nb], 0, 0, 0);
        oacc[nb] = __builtin_amdgcn_mfma_f32_16x16x32_bf16(pa1, vf1, oacc[nb], 0, 0, 0);
      }
      __builtin_amdgcn_s_setprio(0);
      __syncthreads();  // all reads of buf cur done; drains staged loads for buf cur^1
    }
#pragma unroll
    for (int nb = 0; nb < 8; nb++)
#pragma unroll
      for (int r = 0; r < 4; r++) {
        int row = q0 + lhi * 4 + r;
        float v = oacc[nb][r] / lrun[r];
        Ao[((long)(b * SEQ + row)) * DM + h * HD + nb * 16 + l15] = f2bf(v);
      }
  }
#undef STAGE
}

// ---------------- launcher ----------------
extern "C" void kernel_launch(void* const* d_in, const int* in_sizes, int n_in,
                              void* d_out, int out_size, void* d_ws, size_t ws_size,
                              hipStream_t stream) {
  const float* x    = (const float*)d_in[0];
  const float* amsk = (const float*)d_in[1];
  const float* Wqkv = (const float*)d_in[2];
  const float* bqkv = (const float*)d_in[3];
  const float* Wout = (const float*)d_in[4];
  const float* bout = (const float*)d_in[5];
  float* out = (float*)d_out;

  char* ws = (char*)d_ws;
  u16* xb  = (u16*)(ws + 0);                   // [4096][2048]
  u16* WqT = (u16*)(ws + 16777216UL);          // [6144][2048]
  u16* WoT = (u16*)(ws + 41943040UL);          // [2048][2048]
  u16* Qb  = (u16*)(ws + 50331648UL);          // [B*H][S][HD]
  u16* Kb  = (u16*)(ws + 67108864UL);          // [B*H][S][HD]
  u16* Vt  = (u16*)(ws + 83886080UL);          // [B*H][HD][S]
  u16* Ao  = (u16*)(ws + 100663296UL);         // [4096][2048]

  k_cvt<<<8192, 256, 0, stream>>>(x, xb, (MROWS * DM) / 4);
  k_transpose<<<dim3(N3 / 32, DM / 32), 256, 0, stream>>>(Wqkv, WqT, DM, N3);
  k_transpose<<<dim3(DM / 32, DM / 32), 256, 0, stream>>>(Wout, WoT, DM, DM);
  k_gemm_qkv<<<dim3(32, 32), 256, 0, stream>>>(xb, WqT, bqkv, Qb, Kb, Vt);
  k_attn<<<dim3(SEQ / 128, BATCH * NH), 256, 0, stream>>>(Qb, Kb, Vt, amsk, Ao);
  k_gemm_out<<<dim3(16, 32), 256, 0, stream>>>(Ao, WoT, bout, out);
}

// Round 14
// 286.653 us; speedup vs baseline: 1.1856x; 1.0278x over previous
//
#include <hip/hip_runtime.h>
#include <hip/hip_bf16.h>

typedef __bf16 bf16x8 __attribute__((ext_vector_type(8)));
typedef float f32x4 __attribute__((ext_vector_type(4)));
typedef unsigned short u16;

constexpr int BATCH = 2, SEQ = 2048, DM = 2048, NH = 16, HD = 128;
constexpr int N3 = 3 * DM;          // 6144
constexpr int MROWS = BATCH * SEQ;  // 4096

__device__ __forceinline__ u16 f2bf(float f) {
  unsigned u = __builtin_bit_cast(unsigned, f);
  unsigned r = 0x7FFFu + ((u >> 16) & 1u);
  return (u16)((u + r) >> 16);
}

// async global->LDS, 16B per lane; LDS dest = wave-uniform base + lane*16
__device__ __forceinline__ void glds16(const u16* g, u16* l) {
  __builtin_amdgcn_global_load_lds(
      (const __attribute__((address_space(1))) unsigned*)(const void*)g,
      (__attribute__((address_space(3))) unsigned*)(void*)l, 16, 0, 0);
}

// ---------------- convert f32 -> bf16 (n4 = n/4 float4 groups) ----------------
__global__ __launch_bounds__(256) void k_cvt(const float* __restrict__ in,
                                             u16* __restrict__ out, int n4) {
  int i = blockIdx.x * blockDim.x + threadIdx.x;
  if (i >= n4) return;
  float4 v = reinterpret_cast<const float4*>(in)[i];
  ushort4 o;
  o.x = f2bf(v.x); o.y = f2bf(v.y); o.z = f2bf(v.z); o.w = f2bf(v.w);
  reinterpret_cast<ushort4*>(out)[i] = o;
}

// ---------------- transpose f32 [K][N] -> bf16 [N][K] ----------------
__global__ __launch_bounds__(256) void k_transpose(const float* __restrict__ in,
                                                   u16* __restrict__ out, int K, int N) {
  __shared__ float tile[32][33];
  int n0 = blockIdx.x * 32, k0 = blockIdx.y * 32;
  int tx = threadIdx.x & 31, ty = threadIdx.x >> 5;  // 32 x 8
#pragma unroll
  for (int r = ty; r < 32; r += 8) tile[r][tx] = in[(long)(k0 + r) * N + n0 + tx];
  __syncthreads();
#pragma unroll
  for (int r = ty; r < 32; r += 8) out[(long)(n0 + r) * K + k0 + tx] = f2bf(tile[tx][r]);
}

// ---------------- QKV GEMM: 128x192 tile, BK=64, 4 waves, 8-phase, 2 blocks/CU ----------------
__global__ __launch_bounds__(256, 2) void k_gemm_qkv(const u16* __restrict__ A,
                                                     const u16* __restrict__ Bt,
                                                     const float* __restrict__ bias,
                                                     u16* __restrict__ Qb, u16* __restrict__ Kb,
                                                     u16* __restrict__ Vt) {
  constexpr int K = DM;        // 2048
  constexpr int NKT = K / 64;  // 32 K-tiles
  constexpr int NIT = NKT / 2; // 16 iterations
  __shared__ u16 LA[2 * 128 * 64];  // 32 KB
  __shared__ u16 LB[2 * 192 * 64];  // 48 KB
  int lin = blockIdx.y * 32 + blockIdx.x;
  int wid = (lin & 7) * 128 + (lin >> 3);
  int m0 = (wid & 31) * 128;
  int n0 = (wid >> 5) * 192;
  int t = threadIdx.x, lane = t & 63, w = t >> 6;
  int l15 = lane & 15, lhi = lane >> 4;
  int wrow = w >> 1, wcol = w & 1;  // 2x2 wave grid; per-wave out 64x96
  int srow = t >> 3;                       // 0..31
  int scol = ((t & 7) ^ (srow & 7)) * 8;

#define STG_A(TILE, IDX) do {                                                      \
    int kb_ = ((TILE) < NKT ? (TILE) : NKT - 1) * 64;                              \
    glds16(A + (long)(m0 + (IDX) * 32 + srow) * K + kb_ + scol,                    \
           LA + ((TILE) & 1) * 8192 + (IDX) * 2048 + w * 512);                     \
  } while (0)
#define STG_B(TILE, IDX) do {                                                      \
    int kb_ = ((TILE) < NKT ? (TILE) : NKT - 1) * 64;                              \
    glds16(Bt + (long)(n0 + (IDX) * 32 + srow) * K + kb_ + scol,                   \
           LB + ((TILE) & 1) * 12288 + (IDX) * 2048 + w * 512);                    \
  } while (0)

  bf16x8 af[2][2], bfr0[3][2], bfr1[3][2];
  f32x4 acc[4][6] = {};

#define LDA_FRAGS(BUF, QM) do {                                                    \
    _Pragma("unroll") for (int mi = 0; mi < 2; mi++) {                             \
      int rA = wrow * 64 + ((QM) * 2 + mi) * 16 + l15;                             \
      _Pragma("unroll") for (int kk = 0; kk < 2; kk++)                             \
        af[mi][kk] = *(const bf16x8*)(LA + (BUF) * 8192 + rA * 64 +                \
                                      (((kk * 4 + lhi) ^ (rA & 7)) * 8));          \
    } } while (0)
#define LDB_FRAGS(BUF, QN, DST) do {                                               \
    _Pragma("unroll") for (int ni = 0; ni < 3; ni++) {                             \
      int rB = wcol * 96 + ((QN) * 3 + ni) * 16 + l15;                             \
      _Pragma("unroll") for (int kk = 0; kk < 2; kk++)                             \
        DST[ni][kk] = *(const bf16x8*)(LB + (BUF) * 12288 + rB * 64 +              \
                                       (((kk * 4 + lhi) ^ (rB & 7)) * 8));         \
    } } while (0)
#define MM(QM, QN, BF) do {                                                        \
    __builtin_amdgcn_s_setprio(1);                                                 \
    _Pragma("unroll") for (int mi = 0; mi < 2; mi++)                               \
    _Pragma("unroll") for (int ni = 0; ni < 3; ni++)                               \
    _Pragma("unroll") for (int kk = 0; kk < 2; kk++)                               \
      acc[(QM) * 2 + mi][(QN) * 3 + ni] = __builtin_amdgcn_mfma_f32_16x16x32_bf16( \
          af[mi][kk], BF[ni][kk], acc[(QM) * 2 + mi][(QN) * 3 + ni], 0, 0, 0);     \
    __builtin_amdgcn_s_setprio(0);                                                 \
  } while (0)
#define BAR __builtin_amdgcn_s_barrier()
#define LG0 do { asm volatile("s_waitcnt lgkmcnt(0)" ::: "memory");                \
                 __builtin_amdgcn_sched_barrier(0); } while (0)
#define VMW6 do { asm volatile("s_waitcnt vmcnt(6)" ::: "memory");                 \
                  __builtin_amdgcn_sched_barrier(0); } while (0)

  STG_A(0, 0); STG_A(0, 1); STG_A(0, 2); STG_A(0, 3);
  STG_B(0, 0); STG_B(0, 1); STG_B(0, 2); STG_B(0, 3); STG_B(0, 4); STG_B(0, 5);
  STG_B(1, 0); STG_B(1, 1); STG_B(1, 2); STG_B(1, 3); STG_B(1, 4); STG_B(1, 5);
  VMW6; BAR;

  for (int it = 0; it < NIT; it++) {
    int k1 = 2 * it + 1, k2 = 2 * it + 2, k3 = 2 * it + 3;
    LDA_FRAGS(0, 0); LDB_FRAGS(0, 0, bfr0);
    STG_A(k1, 0); STG_A(k1, 1); STG_A(k1, 2);      BAR; LG0; MM(0, 0, bfr0); BAR;  // ph1
    LDB_FRAGS(0, 1, bfr1);
    STG_A(k1, 3);                                  BAR; LG0; MM(0, 1, bfr1); BAR;  // ph2
    LDA_FRAGS(0, 1);
    STG_B(k2, 0); STG_B(k2, 1); STG_B(k2, 2);      BAR; LG0; MM(1, 0, bfr0); BAR;  // ph3
    STG_B(k2, 3); STG_B(k2, 4); STG_B(k2, 5);
    VMW6;                                          BAR;      MM(1, 1, bfr1); BAR;  // ph4
    LDA_FRAGS(1, 0); LDB_FRAGS(1, 0, bfr0);
    STG_A(k2, 0); STG_A(k2, 1); STG_A(k2, 2);      BAR; LG0; MM(0, 0, bfr0); BAR;  // ph5
    LDB_FRAGS(1, 1, bfr1);
    STG_A(k2, 3);                                  BAR; LG0; MM(0, 1, bfr1); BAR;  // ph6
    LDA_FRAGS(1, 1);
    STG_B(k3, 0); STG_B(k3, 1); STG_B(k3, 2);      BAR; LG0; MM(1, 0, bfr0); BAR;  // ph7
    STG_B(k3, 3); STG_B(k3, 4); STG_B(k3, 5);
    VMW6;                                          BAR;      MM(1, 1, bfr1); BAR;  // ph8
  }
#undef STG_A
#undef STG_B
#undef LDA_FRAGS
#undef LDB_FRAGS
#undef MM
#undef BAR
#undef LG0
#undef VMW6

#pragma unroll
  for (int mi = 0; mi < 4; mi++)
#pragma unroll
    for (int ni = 0; ni < 6; ni++) {
      int col = n0 + wcol * 96 + ni * 16 + l15;
      float bv = bias[col];
      int sec = col >> 11, dn = col & 2047, h = dn >> 7, hd = dn & 127;
#pragma unroll
      for (int r = 0; r < 4; r++) {
        int row = m0 + wrow * 64 + mi * 16 + lhi * 4 + r;
        int bb = row >> 11, ss = row & 2047;
        u16 val = f2bf(acc[mi][ni][r] + bv);
        if (sec == 0)
          Qb[(((long)(bb * NH + h)) * SEQ + ss) * HD + hd] = val;
        else if (sec == 1)
          Kb[(((long)(bb * NH + h)) * SEQ + ss) * HD + hd] = val;
        else
          Vt[(((long)(bb * NH + h)) * HD + hd) * SEQ + ss] = val;
      }
    }
}

// ---------------- output GEMM: 128x128 tile, BK=64, 4 waves, 8-phase, 2 blocks/CU ----------------
__global__ __launch_bounds__(256, 2) void k_gemm_out(const u16* __restrict__ A,
                                                     const u16* __restrict__ Bt,
                                                     const float* __restrict__ bias,
                                                     float* __restrict__ Out) {
  constexpr int K = DM, N = DM;
  constexpr int NKT = K / 64;  // 32
  constexpr int NIT = NKT / 2; // 16
  __shared__ u16 LA[2 * 128 * 64];  // 32 KB
  __shared__ u16 LB[2 * 128 * 64];  // 32 KB
  int lin = blockIdx.y * 16 + blockIdx.x;
  int wid = (lin & 7) * 64 + (lin >> 3);
  int m0 = (wid & 31) * 128;
  int n0 = (wid >> 5) * 128;
  int t = threadIdx.x, lane = t & 63, w = t >> 6;
  int l15 = lane & 15, lhi = lane >> 4;
  int wrow = w >> 1, wcol = w & 1;  // 2x2 waves; per-wave out 64x64
  int srow = t >> 3;                // 0..31
  int scol = ((t & 7) ^ (srow & 7)) * 8;

#define STG_A(TILE, IDX) do {                                                      \
    int kb_ = ((TILE) < NKT ? (TILE) : NKT - 1) * 64;                              \
    glds16(A + (long)(m0 + (IDX) * 32 + srow) * K + kb_ + scol,                    \
           LA + ((TILE) & 1) * 8192 + (IDX) * 2048 + w * 512);                     \
  } while (0)
#define STG_B(TILE, IDX) do {                                                      \
    int kb_ = ((TILE) < NKT ? (TILE) : NKT - 1) * 64;                              \
    glds16(Bt + (long)(n0 + (IDX) * 32 + srow) * K + kb_ + scol,                   \
           LB + ((TILE) & 1) * 8192 + (IDX) * 2048 + w * 512);                     \
  } while (0)

  bf16x8 af[2][2], bfr0[2][2], bfr1[2][2];
  f32x4 acc[4][4] = {};

#define LDA_FRAGS(BUF, QM) do {                                                    \
    _Pragma("unroll") for (int mi = 0; mi < 2; mi++) {                             \
      int rA = wrow * 64 + ((QM) * 2 + mi) * 16 + l15;                             \
      _Pragma("unroll") for (int kk = 0; kk < 2; kk++)                             \
        af[mi][kk] = *(const bf16x8*)(LA + (BUF) * 8192 + rA * 64 +                \
                                      (((kk * 4 + lhi) ^ (rA & 7)) * 8));          \
    } } while (0)
#define LDB_FRAGS(BUF, QN, DST) do {                                               \
    _Pragma("unroll") for (int ni = 0; ni < 2; ni++) {                             \
      int rB = wcol * 64 + ((QN) * 2 + ni) * 16 + l15;                             \
      _Pragma("unroll") for (int kk = 0; kk < 2; kk++)                             \
        DST[ni][kk] = *(const bf16x8*)(LB + (BUF) * 8192 + rB * 64 +               \
                                       (((kk * 4 + lhi) ^ (rB & 7)) * 8));         \
    } } while (0)
#define MM(QM, QN, BF) do {                                                        \
    __builtin_amdgcn_s_setprio(1);                                                 \
    _Pragma("unroll") for (int mi = 0; mi < 2; mi++)                               \
    _Pragma("unroll") for (int ni = 0; ni < 2; ni++)                               \
    _Pragma("unroll") for (int kk = 0; kk < 2; kk++)                               \
      acc[(QM) * 2 + mi][(QN) * 2 + ni] = __builtin_amdgcn_mfma_f32_16x16x32_bf16( \
          af[mi][kk], BF[ni][kk], acc[(QM) * 2 + mi][(QN) * 2 + ni], 0, 0, 0);     \
    __builtin_amdgcn_s_setprio(0);                                                 \
  } while (0)
#define BAR __builtin_amdgcn_s_barrier()
#define LG0 do { asm volatile("s_waitcnt lgkmcnt(0)" ::: "memory");                \
                 __builtin_amdgcn_sched_barrier(0); } while (0)
#define VMW4 do { asm volatile("s_waitcnt vmcnt(4)" ::: "memory");                 \
                  __builtin_amdgcn_sched_barrier(0); } while (0)

  STG_A(0, 0); STG_A(0, 1); STG_A(0, 2); STG_A(0, 3);
  STG_B(0, 0); STG_B(0, 1); STG_B(0, 2); STG_B(0, 3);
  STG_B(1, 0); STG_B(1, 1); STG_B(1, 2); STG_B(1, 3);
  VMW4; BAR;

  for (int it = 0; it < NIT; it++) {
    int k1 = 2 * it + 1, k2 = 2 * it + 2, k3 = 2 * it + 3;
    LDA_FRAGS(0, 0); LDB_FRAGS(0, 0, bfr0);
    STG_A(k1, 0); STG_A(k1, 1); STG_A(k1, 2);      BAR; LG0; MM(0, 0, bfr0); BAR;  // ph1
    LDB_FRAGS(0, 1, bfr1);
    STG_A(k1, 3);                                  BAR; LG0; MM(0, 1, bfr1); BAR;  // ph2
    LDA_FRAGS(0, 1);
    STG_B(k2, 0); STG_B(k2, 1); STG_B(k2, 2);      BAR; LG0; MM(1, 0, bfr0); BAR;  // ph3
    STG_B(k2, 3);
    VMW4;                                          BAR;      MM(1, 1, bfr1); BAR;  // ph4
    LDA_FRAGS(1, 0); LDB_FRAGS(1, 0, bfr0);
    STG_A(k2, 0); STG_A(k2, 1); STG_A(k2, 2);      BAR; LG0; MM(0, 0, bfr0); BAR;  // ph5
    LDB_FRAGS(1, 1, bfr1);
    STG_A(k2, 3);                                  BAR; LG0; MM(0, 1, bfr1); BAR;  // ph6
    LDA_FRAGS(1, 1);
    STG_B(k3, 0); STG_B(k3, 1); STG_B(k3, 2);      BAR; LG0; MM(1, 0, bfr0); BAR;  // ph7
    STG_B(k3, 3);
    VMW4;                                          BAR;      MM(1, 1, bfr1); BAR;  // ph8
  }
#undef STG_A
#undef STG_B
#undef LDA_FRAGS
#undef LDB_FRAGS
#undef MM
#undef BAR
#undef LG0
#undef VMW4

#pragma unroll
  for (int mi = 0; mi < 4; mi++)
#pragma unroll
    for (int ni = 0; ni < 4; ni++) {
      int col = n0 + wcol * 64 + ni * 16 + l15;
      float bv = bias[col];
#pragma unroll
      for (int r = 0; r < 4; r++) {
        int row = m0 + wrow * 64 + mi * 16 + lhi * 4 + r;
        Out[(long)row * N + col] = acc[mi][ni][r] + bv;
      }
    }
}

// ---------------- flash attention: 1 q-tile per block, LPT dispatch, 4 blocks/CU target ----------------
// glds16 async double-buffered K/V (R13 body). Grid (bh=32, qidx=32); qt = 31 - blockIdx.y
// so the 32 longest blocks dispatch first (LPT). No launch_bounds min-waves (R10 lesson);
// live state ~110 VGPR (kst/vst eliminated) should allow 4 waves/SIMD naturally.
__global__ __launch_bounds__(256) void k_attn(const u16* __restrict__ Qb,
                                              const u16* __restrict__ Kb,
                                              const u16* __restrict__ Vt,
                                              const float* __restrict__ mask,
                                              u16* __restrict__ Ao) {
  constexpr int NT = SEQ / 64;  // 32
  int bh = blockIdx.x;          // b*NH + h
  int qt = (NT - 1) - blockIdx.y;  // longest first across all heads
  int t = threadIdx.x, w = t >> 6, lane = t & 63;
  int l15 = lane & 15, lhi = lane >> 4;
  int b = bh >> 4, h = bh & 15;
  const u16* Qh = Qb + (long)bh * SEQ * HD;
  const u16* Kh = Kb + (long)bh * SEQ * HD;
  const u16* Vh = Vt + (long)bh * HD * SEQ;
  const float* mh = mask + h * SEQ;

  __shared__ u16 Ks[2][64 * 128];   // 32 KB
  __shared__ u16 Vs[2][128 * 64];   // 32 KB
  __shared__ u16 p_lds[4 * 16 * 64];
  u16* pw = p_lds + w * (16 * 64);

  // staging source coords (chunk c = i*256+t; source col pre-swizzled; LDS dest linear)
  int krow[4], kcolS[4], vrow[4], vcolS[4];
#pragma unroll
  for (int i = 0; i < 4; i++) {
    int c = i * 256 + t;
    krow[i] = c >> 4; kcolS[i] = ((c & 15) ^ ((c >> 4) & 7)) * 8;   // K: 64 x 128
    vrow[i] = c >> 3; vcolS[i] = ((c & 7) ^ ((c >> 3) & 7)) * 8;    // V: 128 x 64
  }

#define STAGE(KT, BUF) do {                                                        \
    int kb_ = (KT) * 64;                                                           \
    _Pragma("unroll") for (int i = 0; i < 4; i++)                                  \
      glds16(Kh + (long)(kb_ + krow[i]) * HD + kcolS[i],                           \
             &Ks[BUF][(i * 256 + w * 64) * 8]);                                    \
    _Pragma("unroll") for (int i = 0; i < 4; i++)                                  \
      glds16(Vh + (long)vrow[i] * SEQ + kb_ + vcolS[i],                            \
             &Vs[BUF][(i * 256 + w * 64) * 8]);                                    \
  } while (0)

  const float sm_scale = 0.08838834764831845f;  // 1/sqrt(128)
  int q0 = qt * 64 + w * 16;
  int nt = qt + 1;

  bf16x8 qf[4];
#pragma unroll
  for (int kc = 0; kc < 4; kc++)
    qf[kc] = *(const bf16x8*)(Qh + (long)(q0 + l15) * HD + kc * 32 + lhi * 8);

  int rowr[4];
#pragma unroll
  for (int r = 0; r < 4; r++) rowr[r] = q0 + lhi * 4 + r;

  float mrun[4], lrun[4];
  f32x4 oacc[8] = {};
#pragma unroll
  for (int r = 0; r < 4; r++) { mrun[r] = -1e30f; lrun[r] = 0.f; }

  STAGE(0, 0);
  __syncthreads();  // drains vmcnt: tile 0 resident

  for (int kt = 0; kt < nt; kt++) {
    int cur = kt & 1;
    if (kt + 1 < nt) STAGE(kt + 1, cur ^ 1);  // async into other buffer
    bool diag = (kt == nt - 1);
    int kb = kt * 64;
    const u16* Ksg = Ks[cur];
    const u16* Vsg = Vs[cur];
    float bvv[4];
#pragma unroll
    for (int cb = 0; cb < 4; cb++) bvv[cb] = mh[kb + cb * 16 + l15];
    f32x4 sc[4] = {};
    __builtin_amdgcn_s_setprio(1);
#pragma unroll
    for (int kc = 0; kc < 4; kc++)
#pragma unroll
      for (int cb = 0; cb < 4; cb++) {
        int rr = cb * 16 + l15;
        bf16x8 kf = *(const bf16x8*)(Ksg + rr * 128 + ((kc * 32 + lhi * 8) ^ ((rr & 7) << 3)));
        sc[cb] = __builtin_amdgcn_mfma_f32_16x16x32_bf16(qf[kc], kf, sc[cb], 0, 0, 0);
      }
    __builtin_amdgcn_s_setprio(0);
    float p[4][4], tmax[4];
#pragma unroll
    for (int cb = 0; cb < 4; cb++) {
      int col = kb + cb * 16 + l15;
#pragma unroll
      for (int r = 0; r < 4; r++) {
        float v = sc[cb][r] * sm_scale + bvv[cb];
        if (diag) v = (col <= rowr[r]) ? v : -1e30f;
        p[cb][r] = v;
      }
    }
#pragma unroll
    for (int r = 0; r < 4; r++)
      tmax[r] = fmaxf(fmaxf(p[0][r], p[1][r]), fmaxf(p[2][r], p[3][r]));
    float alpha[4];
#pragma unroll
    for (int r = 0; r < 4; r++) {
      float v = tmax[r];
      v = fmaxf(v, __shfl_xor(v, 1));
      v = fmaxf(v, __shfl_xor(v, 2));
      v = fmaxf(v, __shfl_xor(v, 4));
      v = fmaxf(v, __shfl_xor(v, 8));
      float mnew = fmaxf(mrun[r], v);
      alpha[r] = __expf(mrun[r] - mnew);
      mrun[r] = mnew;
      float s = 0.f;
#pragma unroll
      for (int cb = 0; cb < 4; cb++) {
        float e = __expf(p[cb][r] - mnew);
        p[cb][r] = e;
        s += e;
      }
      s += __shfl_xor(s, 1); s += __shfl_xor(s, 2);
      s += __shfl_xor(s, 4); s += __shfl_xor(s, 8);
      lrun[r] = lrun[r] * alpha[r] + s;
    }
#pragma unroll
    for (int nb = 0; nb < 8; nb++)
#pragma unroll
      for (int r = 0; r < 4; r++) oacc[nb][r] *= alpha[r];
#pragma unroll
    for (int cb = 0; cb < 4; cb++)
#pragma unroll
      for (int r = 0; r < 4; r++) {
        int rr = lhi * 4 + r;
        pw[(rr * 64 + cb * 16 + l15) ^ ((rr & 7) << 3)] = f2bf(p[cb][r]);
      }
    asm volatile("s_waitcnt lgkmcnt(0)" ::: "memory");
    bf16x8 pa0 = *(const bf16x8*)(pw + ((l15 * 64 + lhi * 8) ^ ((l15 & 7) << 3)));
    bf16x8 pa1 = *(const bf16x8*)(pw + ((l15 * 64 + 32 + lhi * 8) ^ ((l15 & 7) << 3)));
    __builtin_amdgcn_s_setprio(1);
#pragma unroll
    for (int nb = 0; nb < 8; nb++) {
      int rr = nb * 16 + l15;
      bf16x8 vf0 = *(const bf16x8*)(Vsg + rr * 64 + ((lhi * 8) ^ ((rr & 7) << 3)));
      bf16x8 vf1 = *(const bf16x8*)(Vsg + rr * 64 + ((32 + lhi * 8) ^ ((rr & 7) << 3)));
      oacc[nb] = __builtin_amdgcn_mfma_f32_16x16x32_bf16(pa0, vf0, oacc[nb], 0, 0, 0);
      oacc[nb] = __builtin_amdgcn_mfma_f32_16x16x32_bf16(pa1, vf1, oacc[nb], 0, 0, 0);
    }
    __builtin_amdgcn_s_setprio(0);
    __syncthreads();  // all reads of buf cur done; drains staged loads for buf cur^1
  }
#pragma unroll
  for (int nb = 0; nb < 8; nb++)
#pragma unroll
    for (int r = 0; r < 4; r++) {
      int row = q0 + lhi * 4 + r;
      float v = oacc[nb][r] / lrun[r];
      Ao[((long)(b * SEQ + row)) * DM + h * HD + nb * 16 + l15] = f2bf(v);
    }
#undef STAGE
}

// ---------------- launcher ----------------
extern "C" void kernel_launch(void* const* d_in, const int* in_sizes, int n_in,
                              void* d_out, int out_size, void* d_ws, size_t ws_size,
                              hipStream_t stream) {
  const float* x    = (const float*)d_in[0];
  const float* amsk = (const float*)d_in[1];
  const float* Wqkv = (const float*)d_in[2];
  const float* bqkv = (const float*)d_in[3];
  const float* Wout = (const float*)d_in[4];
  const float* bout = (const float*)d_in[5];
  float* out = (float*)d_out;

  char* ws = (char*)d_ws;
  u16* xb  = (u16*)(ws + 0);                   // [4096][2048]
  u16* WqT = (u16*)(ws + 16777216UL);          // [6144][2048]
  u16* WoT = (u16*)(ws + 41943040UL);          // [2048][2048]
  u16* Qb  = (u16*)(ws + 50331648UL);          // [B*H][S][HD]
  u16* Kb  = (u16*)(ws + 67108864UL);          // [B*H][S][HD]
  u16* Vt  = (u16*)(ws + 83886080UL);          // [B*H][HD][S]
  u16* Ao  = (u16*)(ws + 100663296UL);         // [4096][2048]

  k_cvt<<<8192, 256, 0, stream>>>(x, xb, (MROWS * DM) / 4);
  k_transpose<<<dim3(N3 / 32, DM / 32), 256, 0, stream>>>(Wqkv, WqT, DM, N3);
  k_transpose<<<dim3(DM / 32, DM / 32), 256, 0, stream>>>(Wout, WoT, DM, DM);
  k_gemm_qkv<<<dim3(32, 32), 256, 0, stream>>>(xb, WqT, bqkv, Qb, Kb, Vt);
  k_attn<<<dim3(BATCH * NH, SEQ / 64), 256, 0, stream>>>(Qb, Kb, Vt, amsk, Ao);
  k_gemm_out<<<dim3(16, 32), 256, 0, stream>>>(Ao, WoT, bout, out);
}

// Round 15
// 280.112 us; speedup vs baseline: 1.2133x; 1.0234x over previous
//
#include <hip/hip_runtime.h>
#include <hip/hip_bf16.h>

typedef __bf16 bf16x8 __attribute__((ext_vector_type(8)));
typedef float f32x4 __attribute__((ext_vector_type(4)));
typedef unsigned short u16;

constexpr int BATCH = 2, SEQ = 2048, DM = 2048, NH = 16, HD = 128;
constexpr int N3 = 3 * DM;          // 6144
constexpr int MROWS = BATCH * SEQ;  // 4096

__device__ __forceinline__ u16 f2bf(float f) {
  unsigned u = __builtin_bit_cast(unsigned, f);
  unsigned r = 0x7FFFu + ((u >> 16) & 1u);
  return (u16)((u + r) >> 16);
}

// async global->LDS, 16B per lane; LDS dest = wave-uniform base + lane*16
__device__ __forceinline__ void glds16(const u16* g, u16* l) {
  __builtin_amdgcn_global_load_lds(
      (const __attribute__((address_space(1))) unsigned*)(const void*)g,
      (__attribute__((address_space(3))) unsigned*)(void*)l, 16, 0, 0);
}

// ---------------- convert f32 -> bf16 (n4 = n/4 float4 groups) ----------------
__global__ __launch_bounds__(256) void k_cvt(const float* __restrict__ in,
                                             u16* __restrict__ out, int n4) {
  int i = blockIdx.x * blockDim.x + threadIdx.x;
  if (i >= n4) return;
  float4 v = reinterpret_cast<const float4*>(in)[i];
  ushort4 o;
  o.x = f2bf(v.x); o.y = f2bf(v.y); o.z = f2bf(v.z); o.w = f2bf(v.w);
  reinterpret_cast<ushort4*>(out)[i] = o;
}

// ---------------- transpose f32 [K][N] -> bf16 [N][K] ----------------
__global__ __launch_bounds__(256) void k_transpose(const float* __restrict__ in,
                                                   u16* __restrict__ out, int K, int N) {
  __shared__ float tile[32][33];
  int n0 = blockIdx.x * 32, k0 = blockIdx.y * 32;
  int tx = threadIdx.x & 31, ty = threadIdx.x >> 5;  // 32 x 8
#pragma unroll
  for (int r = ty; r < 32; r += 8) tile[r][tx] = in[(long)(k0 + r) * N + n0 + tx];
  __syncthreads();
#pragma unroll
  for (int r = ty; r < 32; r += 8) out[(long)(n0 + r) * K + k0 + tx] = f2bf(tile[tx][r]);
}

// ---------------- QKV GEMM: 128x192 tile, BK=64, 4 waves, 4-PHASE, 2 blocks/CU ----------------
// Merged from 8-phase: per K-tile = 2 phases of 24 MFMA each (halves barrier count).
// Counted vmcnt(6) once per K-tile; load-age bookkeeping identical to 8-phase version.
__global__ __launch_bounds__(256, 2) void k_gemm_qkv(const u16* __restrict__ A,
                                                     const u16* __restrict__ Bt,
                                                     const float* __restrict__ bias,
                                                     u16* __restrict__ Qb, u16* __restrict__ Kb,
                                                     u16* __restrict__ Vt) {
  constexpr int K = DM;        // 2048
  constexpr int NKT = K / 64;  // 32 K-tiles
  constexpr int NIT = NKT / 2; // 16 iterations
  __shared__ u16 LA[2 * 128 * 64];  // 32 KB
  __shared__ u16 LB[2 * 192 * 64];  // 48 KB
  int lin = blockIdx.y * 32 + blockIdx.x;
  int wid = (lin & 7) * 128 + (lin >> 3);
  int m0 = (wid & 31) * 128;
  int n0 = (wid >> 5) * 192;
  int t = threadIdx.x, lane = t & 63, w = t >> 6;
  int l15 = lane & 15, lhi = lane >> 4;
  int wrow = w >> 1, wcol = w & 1;  // 2x2 wave grid; per-wave out 64x96
  int srow = t >> 3;                       // 0..31
  int scol = ((t & 7) ^ (srow & 7)) * 8;

#define STG_A(TILE, IDX) do {                                                      \
    int kb_ = ((TILE) < NKT ? (TILE) : NKT - 1) * 64;                              \
    glds16(A + (long)(m0 + (IDX) * 32 + srow) * K + kb_ + scol,                    \
           LA + ((TILE) & 1) * 8192 + (IDX) * 2048 + w * 512);                     \
  } while (0)
#define STG_B(TILE, IDX) do {                                                      \
    int kb_ = ((TILE) < NKT ? (TILE) : NKT - 1) * 64;                              \
    glds16(Bt + (long)(n0 + (IDX) * 32 + srow) * K + kb_ + scol,                   \
           LB + ((TILE) & 1) * 12288 + (IDX) * 2048 + w * 512);                    \
  } while (0)

  bf16x8 af2[4][2], bfr0[3][2], bfr1[3][2];
  f32x4 acc[4][6] = {};

  // load A-fragments for BOTH QM halves (8 ds_read_b128)
#define LDA_ALL(BUF) do {                                                          \
    _Pragma("unroll") for (int mi = 0; mi < 4; mi++) {                             \
      int rA = wrow * 64 + mi * 16 + l15;                                          \
      _Pragma("unroll") for (int kk = 0; kk < 2; kk++)                             \
        af2[mi][kk] = *(const bf16x8*)(LA + (BUF) * 8192 + rA * 64 +               \
                                       (((kk * 4 + lhi) ^ (rA & 7)) * 8));         \
    } } while (0)
#define LDB_FRAGS(BUF, QN, DST) do {                                               \
    _Pragma("unroll") for (int ni = 0; ni < 3; ni++) {                             \
      int rB = wcol * 96 + ((QN) * 3 + ni) * 16 + l15;                             \
      _Pragma("unroll") for (int kk = 0; kk < 2; kk++)                             \
        DST[ni][kk] = *(const bf16x8*)(LB + (BUF) * 12288 + rB * 64 +              \
                                       (((kk * 4 + lhi) ^ (rB & 7)) * 8));         \
    } } while (0)
  // 24-MFMA cluster: both QM halves against one QN third
#define MM2Q(QN, BF) do {                                                          \
    __builtin_amdgcn_s_setprio(1);                                                 \
    _Pragma("unroll") for (int mi = 0; mi < 4; mi++)                               \
    _Pragma("unroll") for (int ni = 0; ni < 3; ni++)                               \
    _Pragma("unroll") for (int kk = 0; kk < 2; kk++)                               \
      acc[mi][(QN) * 3 + ni] = __builtin_amdgcn_mfma_f32_16x16x32_bf16(            \
          af2[mi][kk], BF[ni][kk], acc[mi][(QN) * 3 + ni], 0, 0, 0);               \
    __builtin_amdgcn_s_setprio(0);                                                 \
  } while (0)
#define BAR __builtin_amdgcn_s_barrier()
#define LG0 do { asm volatile("s_waitcnt lgkmcnt(0)" ::: "memory");                \
                 __builtin_amdgcn_sched_barrier(0); } while (0)
#define VMW6 do { asm volatile("s_waitcnt vmcnt(6)" ::: "memory");                 \
                  __builtin_amdgcn_sched_barrier(0); } while (0)

  STG_A(0, 0); STG_A(0, 1); STG_A(0, 2); STG_A(0, 3);
  STG_B(0, 0); STG_B(0, 1); STG_B(0, 2); STG_B(0, 3); STG_B(0, 4); STG_B(0, 5);
  STG_B(1, 0); STG_B(1, 1); STG_B(1, 2); STG_B(1, 3); STG_B(1, 4); STG_B(1, 5);
  VMW6; BAR;

  for (int it = 0; it < NIT; it++) {
    int k1 = 2 * it + 1, k2 = 2 * it + 2, k3 = 2 * it + 3;
    // ---- K-tile 2it (buf0): 2 phases ----
    // entering: B(k1) x6 outstanding
    LDA_ALL(0); LDB_FRAGS(0, 0, bfr0);
    STG_A(k1, 0); STG_A(k1, 1); STG_A(k1, 2); STG_A(k1, 3);
    BAR; LG0; MM2Q(0, bfr0); BAR;                                    // phA (+4 -> 10)
    LDB_FRAGS(0, 1, bfr1);
    STG_B(k2, 0); STG_B(k2, 1); STG_B(k2, 2);
    STG_B(k2, 3); STG_B(k2, 4); STG_B(k2, 5);
    VMW6;  // 16 outstanding: keep newest 6 = B(k2); completes B(k1)+A(k1) for buf1
    BAR; LG0; MM2Q(1, bfr1); BAR;                                    // phB (+6 -> 16->6)
    // ---- K-tile 2it+1 (buf1): 2 phases ----
    LDA_ALL(1); LDB_FRAGS(1, 0, bfr0);
    STG_A(k2, 0); STG_A(k2, 1); STG_A(k2, 2); STG_A(k2, 3);
    BAR; LG0; MM2Q(0, bfr0); BAR;                                    // phC
    LDB_FRAGS(1, 1, bfr1);
    STG_B(k3, 0); STG_B(k3, 1); STG_B(k3, 2);
    STG_B(k3, 3); STG_B(k3, 4); STG_B(k3, 5);
    VMW6;  // completes B(k2)+A(k2) for buf0 next iter
    BAR; LG0; MM2Q(1, bfr1); BAR;                                    // phD
  }
#undef STG_A
#undef STG_B
#undef LDA_ALL
#undef LDB_FRAGS
#undef MM2Q
#undef BAR
#undef LG0
#undef VMW6

#pragma unroll
  for (int mi = 0; mi < 4; mi++)
#pragma unroll
    for (int ni = 0; ni < 6; ni++) {
      int col = n0 + wcol * 96 + ni * 16 + l15;
      float bv = bias[col];
      int sec = col >> 11, dn = col & 2047, h = dn >> 7, hd = dn & 127;
#pragma unroll
      for (int r = 0; r < 4; r++) {
        int row = m0 + wrow * 64 + mi * 16 + lhi * 4 + r;
        int bb = row >> 11, ss = row & 2047;
        u16 val = f2bf(acc[mi][ni][r] + bv);
        if (sec == 0)
          Qb[(((long)(bb * NH + h)) * SEQ + ss) * HD + hd] = val;
        else if (sec == 1)
          Kb[(((long)(bb * NH + h)) * SEQ + ss) * HD + hd] = val;
        else
          Vt[(((long)(bb * NH + h)) * HD + hd) * SEQ + ss] = val;
      }
    }
}

// ---------------- output GEMM: 128x128 tile, BK=64, 4 waves, 4-PHASE, 2 blocks/CU ----------------
__global__ __launch_bounds__(256, 2) void k_gemm_out(const u16* __restrict__ A,
                                                     const u16* __restrict__ Bt,
                                                     const float* __restrict__ bias,
                                                     float* __restrict__ Out) {
  constexpr int K = DM, N = DM;
  constexpr int NKT = K / 64;  // 32
  constexpr int NIT = NKT / 2; // 16
  __shared__ u16 LA[2 * 128 * 64];  // 32 KB
  __shared__ u16 LB[2 * 128 * 64];  // 32 KB
  int lin = blockIdx.y * 16 + blockIdx.x;
  int wid = (lin & 7) * 64 + (lin >> 3);
  int m0 = (wid & 31) * 128;
  int n0 = (wid >> 5) * 128;
  int t = threadIdx.x, lane = t & 63, w = t >> 6;
  int l15 = lane & 15, lhi = lane >> 4;
  int wrow = w >> 1, wcol = w & 1;  // 2x2 waves; per-wave out 64x64
  int srow = t >> 3;                // 0..31
  int scol = ((t & 7) ^ (srow & 7)) * 8;

#define STG_A(TILE, IDX) do {                                                      \
    int kb_ = ((TILE) < NKT ? (TILE) : NKT - 1) * 64;                              \
    glds16(A + (long)(m0 + (IDX) * 32 + srow) * K + kb_ + scol,                    \
           LA + ((TILE) & 1) * 8192 + (IDX) * 2048 + w * 512);                     \
  } while (0)
#define STG_B(TILE, IDX) do {                                                      \
    int kb_ = ((TILE) < NKT ? (TILE) : NKT - 1) * 64;                              \
    glds16(Bt + (long)(n0 + (IDX) * 32 + srow) * K + kb_ + scol,                   \
           LB + ((TILE) & 1) * 8192 + (IDX) * 2048 + w * 512);                     \
  } while (0)

  bf16x8 af2[4][2], bfr0[2][2], bfr1[2][2];
  f32x4 acc[4][4] = {};

#define LDA_ALL(BUF) do {                                                          \
    _Pragma("unroll") for (int mi = 0; mi < 4; mi++) {                             \
      int rA = wrow * 64 + mi * 16 + l15;                                          \
      _Pragma("unroll") for (int kk = 0; kk < 2; kk++)                             \
        af2[mi][kk] = *(const bf16x8*)(LA + (BUF) * 8192 + rA * 64 +               \
                                       (((kk * 4 + lhi) ^ (rA & 7)) * 8));         \
    } } while (0)
#define LDB_FRAGS(BUF, QN, DST) do {                                               \
    _Pragma("unroll") for (int ni = 0; ni < 2; ni++) {                             \
      int rB = wcol * 64 + ((QN) * 2 + ni) * 16 + l15;                             \
      _Pragma("unroll") for (int kk = 0; kk < 2; kk++)                             \
        DST[ni][kk] = *(const bf16x8*)(LB + (BUF) * 8192 + rB * 64 +               \
                                       (((kk * 4 + lhi) ^ (rB & 7)) * 8));         \
    } } while (0)
#define MM2Q(QN, BF) do {                                                          \
    __builtin_amdgcn_s_setprio(1);                                                 \
    _Pragma("unroll") for (int mi = 0; mi < 4; mi++)                               \
    _Pragma("unroll") for (int ni = 0; ni < 2; ni++)                               \
    _Pragma("unroll") for (int kk = 0; kk < 2; kk++)                               \
      acc[mi][(QN) * 2 + ni] = __builtin_amdgcn_mfma_f32_16x16x32_bf16(            \
          af2[mi][kk], BF[ni][kk], acc[mi][(QN) * 2 + ni], 0, 0, 0);               \
    __builtin_amdgcn_s_setprio(0);                                                 \
  } while (0)
#define BAR __builtin_amdgcn_s_barrier()
#define LG0 do { asm volatile("s_waitcnt lgkmcnt(0)" ::: "memory");                \
                 __builtin_amdgcn_sched_barrier(0); } while (0)
#define VMW4 do { asm volatile("s_waitcnt vmcnt(4)" ::: "memory");                 \
                  __builtin_amdgcn_sched_barrier(0); } while (0)

  STG_A(0, 0); STG_A(0, 1); STG_A(0, 2); STG_A(0, 3);
  STG_B(0, 0); STG_B(0, 1); STG_B(0, 2); STG_B(0, 3);
  STG_B(1, 0); STG_B(1, 1); STG_B(1, 2); STG_B(1, 3);
  VMW4; BAR;

  for (int it = 0; it < NIT; it++) {
    int k1 = 2 * it + 1, k2 = 2 * it + 2, k3 = 2 * it + 3;
    // ---- K-tile 2it (buf0) ----  entering: B(k1) x4
    LDA_ALL(0); LDB_FRAGS(0, 0, bfr0);
    STG_A(k1, 0); STG_A(k1, 1); STG_A(k1, 2); STG_A(k1, 3);
    BAR; LG0; MM2Q(0, bfr0); BAR;                                    // phA (+4 -> 8)
    LDB_FRAGS(0, 1, bfr1);
    STG_B(k2, 0); STG_B(k2, 1); STG_B(k2, 2); STG_B(k2, 3);
    VMW4;  // 12 outstanding: keep newest 4 = B(k2); completes B(k1)+A(k1)
    BAR; LG0; MM2Q(1, bfr1); BAR;                                    // phB
    // ---- K-tile 2it+1 (buf1) ----
    LDA_ALL(1); LDB_FRAGS(1, 0, bfr0);
    STG_A(k2, 0); STG_A(k2, 1); STG_A(k2, 2); STG_A(k2, 3);
    BAR; LG0; MM2Q(0, bfr0); BAR;                                    // phC
    LDB_FRAGS(1, 1, bfr1);
    STG_B(k3, 0); STG_B(k3, 1); STG_B(k3, 2); STG_B(k3, 3);
    VMW4;  // completes B(k2)+A(k2)
    BAR; LG0; MM2Q(1, bfr1); BAR;                                    // phD
  }
#undef STG_A
#undef STG_B
#undef LDA_ALL
#undef LDB_FRAGS
#undef MM2Q
#undef BAR
#undef LG0
#undef VMW4

#pragma unroll
  for (int mi = 0; mi < 4; mi++)
#pragma unroll
    for (int ni = 0; ni < 4; ni++) {
      int col = n0 + wcol * 64 + ni * 16 + l15;
      float bv = bias[col];
#pragma unroll
      for (int r = 0; r < 4; r++) {
        int row = m0 + wrow * 64 + mi * 16 + lhi * 4 + r;
        Out[(long)row * N + col] = acc[mi][ni][r] + bv;
      }
    }
}

// ---------------- flash attention: 1 q-tile per block, LPT dispatch (R14 proven) ----------------
__global__ __launch_bounds__(256) void k_attn(const u16* __restrict__ Qb,
                                              const u16* __restrict__ Kb,
                                              const u16* __restrict__ Vt,
                                              const float* __restrict__ mask,
                                              u16* __restrict__ Ao) {
  constexpr int NT = SEQ / 64;  // 32
  int bh = blockIdx.x;          // b*NH + h
  int qt = (NT - 1) - blockIdx.y;  // longest first across all heads
  int t = threadIdx.x, w = t >> 6, lane = t & 63;
  int l15 = lane & 15, lhi = lane >> 4;
  int b = bh >> 4, h = bh & 15;
  const u16* Qh = Qb + (long)bh * SEQ * HD;
  const u16* Kh = Kb + (long)bh * SEQ * HD;
  const u16* Vh = Vt + (long)bh * HD * SEQ;
  const float* mh = mask + h * SEQ;

  __shared__ u16 Ks[2][64 * 128];   // 32 KB
  __shared__ u16 Vs[2][128 * 64];   // 32 KB
  __shared__ u16 p_lds[4 * 16 * 64];
  u16* pw = p_lds + w * (16 * 64);

  int krow[4], kcolS[4], vrow[4], vcolS[4];
#pragma unroll
  for (int i = 0; i < 4; i++) {
    int c = i * 256 + t;
    krow[i] = c >> 4; kcolS[i] = ((c & 15) ^ ((c >> 4) & 7)) * 8;   // K: 64 x 128
    vrow[i] = c >> 3; vcolS[i] = ((c & 7) ^ ((c >> 3) & 7)) * 8;    // V: 128 x 64
  }

#define STAGE(KT, BUF) do {                                                        \
    int kb_ = (KT) * 64;                                                           \
    _Pragma("unroll") for (int i = 0; i < 4; i++)                                  \
      glds16(Kh + (long)(kb_ + krow[i]) * HD + kcolS[i],                           \
             &Ks[BUF][(i * 256 + w * 64) * 8]);                                    \
    _Pragma("unroll") for (int i = 0; i < 4; i++)                                  \
      glds16(Vh + (long)vrow[i] * SEQ + kb_ + vcolS[i],                            \
             &Vs[BUF][(i * 256 + w * 64) * 8]);                                    \
  } while (0)

  const float sm_scale = 0.08838834764831845f;  // 1/sqrt(128)
  int q0 = qt * 64 + w * 16;
  int nt = qt + 1;

  bf16x8 qf[4];
#pragma unroll
  for (int kc = 0; kc < 4; kc++)
    qf[kc] = *(const bf16x8*)(Qh + (long)(q0 + l15) * HD + kc * 32 + lhi * 8);

  int rowr[4];
#pragma unroll
  for (int r = 0; r < 4; r++) rowr[r] = q0 + lhi * 4 + r;

  float mrun[4], lrun[4];
  f32x4 oacc[8] = {};
#pragma unroll
  for (int r = 0; r < 4; r++) { mrun[r] = -1e30f; lrun[r] = 0.f; }

  STAGE(0, 0);
  __syncthreads();  // drains vmcnt: tile 0 resident

  for (int kt = 0; kt < nt; kt++) {
    int cur = kt & 1;
    if (kt + 1 < nt) STAGE(kt + 1, cur ^ 1);  // async into other buffer
    bool diag = (kt == nt - 1);
    int kb = kt * 64;
    const u16* Ksg = Ks[cur];
    const u16* Vsg = Vs[cur];
    float bvv[4];
#pragma unroll
    for (int cb = 0; cb < 4; cb++) bvv[cb] = mh[kb + cb * 16 + l15];
    f32x4 sc[4] = {};
    __builtin_amdgcn_s_setprio(1);
#pragma unroll
    for (int kc = 0; kc < 4; kc++)
#pragma unroll
      for (int cb = 0; cb < 4; cb++) {
        int rr = cb * 16 + l15;
        bf16x8 kf = *(const bf16x8*)(Ksg + rr * 128 + ((kc * 32 + lhi * 8) ^ ((rr & 7) << 3)));
        sc[cb] = __builtin_amdgcn_mfma_f32_16x16x32_bf16(qf[kc], kf, sc[cb], 0, 0, 0);
      }
    __builtin_amdgcn_s_setprio(0);
    float p[4][4], tmax[4];
#pragma unroll
    for (int cb = 0; cb < 4; cb++) {
      int col = kb + cb * 16 + l15;
#pragma unroll
      for (int r = 0; r < 4; r++) {
        float v = sc[cb][r] * sm_scale + bvv[cb];
        if (diag) v = (col <= rowr[r]) ? v : -1e30f;
        p[cb][r] = v;
      }
    }
#pragma unroll
    for (int r = 0; r < 4; r++)
      tmax[r] = fmaxf(fmaxf(p[0][r], p[1][r]), fmaxf(p[2][r], p[3][r]));
    float alpha[4];
#pragma unroll
    for (int r = 0; r < 4; r++) {
      float v = tmax[r];
      v = fmaxf(v, __shfl_xor(v, 1));
      v = fmaxf(v, __shfl_xor(v, 2));
      v = fmaxf(v, __shfl_xor(v, 4));
      v = fmaxf(v, __shfl_xor(v, 8));
      float mnew = fmaxf(mrun[r], v);
      alpha[r] = __expf(mrun[r] - mnew);
      mrun[r] = mnew;
      float s = 0.f;
#pragma unroll
      for (int cb = 0; cb < 4; cb++) {
        float e = __expf(p[cb][r] - mnew);
        p[cb][r] = e;
        s += e;
      }
      s += __shfl_xor(s, 1); s += __shfl_xor(s, 2);
      s += __shfl_xor(s, 4); s += __shfl_xor(s, 8);
      lrun[r] = lrun[r] * alpha[r] + s;
    }
#pragma unroll
    for (int nb = 0; nb < 8; nb++)
#pragma unroll
      for (int r = 0; r < 4; r++) oacc[nb][r] *= alpha[r];
#pragma unroll
    for (int cb = 0; cb < 4; cb++)
#pragma unroll
      for (int r = 0; r < 4; r++) {
        int rr = lhi * 4 + r;
        pw[(rr * 64 + cb * 16 + l15) ^ ((rr & 7) << 3)] = f2bf(p[cb][r]);
      }
    asm volatile("s_waitcnt lgkmcnt(0)" ::: "memory");
    bf16x8 pa0 = *(const bf16x8*)(pw + ((l15 * 64 + lhi * 8) ^ ((l15 & 7) << 3)));
    bf16x8 pa1 = *(const bf16x8*)(pw + ((l15 * 64 + 32 + lhi * 8) ^ ((l15 & 7) << 3)));
    __builtin_amdgcn_s_setprio(1);
#pragma unroll
    for (int nb = 0; nb < 8; nb++) {
      int rr = nb * 16 + l15;
      bf16x8 vf0 = *(const bf16x8*)(Vsg + rr * 64 + ((lhi * 8) ^ ((rr & 7) << 3)));
      bf16x8 vf1 = *(const bf16x8*)(Vsg + rr * 64 + ((32 + lhi * 8) ^ ((rr & 7) << 3)));
      oacc[nb] = __builtin_amdgcn_mfma_f32_16x16x32_bf16(pa0, vf0, oacc[nb], 0, 0, 0);
      oacc[nb] = __builtin_amdgcn_mfma_f32_16x16x32_bf16(pa1, vf1, oacc[nb], 0, 0, 0);
    }
    __builtin_amdgcn_s_setprio(0);
    __syncthreads();  // all reads of buf cur done; drains staged loads for buf cur^1
  }
#pragma unroll
  for (int nb = 0; nb < 8; nb++)
#pragma unroll
    for (int r = 0; r < 4; r++) {
      int row = q0 + lhi * 4 + r;
      float v = oacc[nb][r] / lrun[r];
      Ao[((long)(b * SEQ + row)) * DM + h * HD + nb * 16 + l15] = f2bf(v);
    }
#undef STAGE
}

// ---------------- launcher ----------------
extern "C" void kernel_launch(void* const* d_in, const int* in_sizes, int n_in,
                              void* d_out, int out_size, void* d_ws, size_t ws_size,
                              hipStream_t stream) {
  const float* x    = (const float*)d_in[0];
  const float* amsk = (const float*)d_in[1];
  const float* Wqkv = (const float*)d_in[2];
  const float* bqkv = (const float*)d_in[3];
  const float* Wout = (const float*)d_in[4];
  const float* bout = (const float*)d_in[5];
  float* out = (float*)d_out;

  char* ws = (char*)d_ws;
  u16* xb  = (u16*)(ws + 0);                   // [4096][2048]
  u16* WqT = (u16*)(ws + 16777216UL);          // [6144][2048]
  u16* WoT = (u16*)(ws + 41943040UL);          // [2048][2048]
  u16* Qb  = (u16*)(ws + 50331648UL);          // [B*H][S][HD]
  u16* Kb  = (u16*)(ws + 67108864UL);          // [B*H][S][HD]
  u16* Vt  = (u16*)(ws + 83886080UL);          // [B*H][HD][S]
  u16* Ao  = (u16*)(ws + 100663296UL);         // [4096][2048]

  k_cvt<<<8192, 256, 0, stream>>>(x, xb, (MROWS * DM) / 4);
  k_transpose<<<dim3(N3 / 32, DM / 32), 256, 0, stream>>>(Wqkv, WqT, DM, N3);
  k_transpose<<<dim3(DM / 32, DM / 32), 256, 0, stream>>>(Wout, WoT, DM, DM);
  k_gemm_qkv<<<dim3(32, 32), 256, 0, stream>>>(xb, WqT, bqkv, Qb, Kb, Vt);
  k_attn<<<dim3(BATCH * NH, SEQ / 64), 256, 0, stream>>>(Qb, Kb, Vt, amsk, Ao);
  k_gemm_out<<<dim3(16, 32), 256, 0, stream>>>(Ao, WoT, bout, out);
}